// Round 5
// baseline (1197.494 us; speedup 1.0000x reference)
//
#include <hip/hip_runtime.h>
#include <math.h>

// ---------------------------------------------------------------------------
// GAT, 3 layers, N=50000, E=800000, H=2 heads, D=64/64/32.
// CSR-by-dst per launch; BM=128/BK=32 register-tiled fp32 GEMM with fused
// el/er + bf16-h epilogue; wave-per-node aggregate gathering bf16 rows
// (uint4 lanes -> 4 or 8 edges per 1KB wave-load).
// ---------------------------------------------------------------------------

typedef unsigned int uint;
typedef unsigned short ushort;

__device__ inline uint f2bf(float f) {  // fp32 -> bf16 bits, RNE
    uint u = __float_as_uint(f);
    return (u + 0x7fffu + ((u >> 16) & 1u)) >> 16;
}

__global__ __launch_bounds__(256) void hist_k(const int* __restrict__ dst, int E,
                                              int* __restrict__ deg) {
    int e = blockIdx.x * 256 + threadIdx.x;
    if (e < E) atomicAdd(&deg[dst[e]], 1);
}

__global__ __launch_bounds__(512) void scan1_k(const int* __restrict__ deg, int n,
                                               int* __restrict__ incl,
                                               int* __restrict__ bsums) {
    __shared__ int sm[512];
    int t = threadIdx.x;
    int i = blockIdx.x * 512 + t;
    int v = (i < n) ? deg[i] : 0;
    sm[t] = v;
    __syncthreads();
    for (int ofs = 1; ofs < 512; ofs <<= 1) {
        int add = (t >= ofs) ? sm[t - ofs] : 0;
        __syncthreads();
        sm[t] += add;
        __syncthreads();
    }
    if (i < n) incl[i] = sm[t];
    if (t == 511) bsums[blockIdx.x] = sm[511];
}

__global__ __launch_bounds__(128) void scan2_k(int* __restrict__ bsums, int nb) {
    __shared__ int sm[128];
    int t = threadIdx.x;
    int v = (t < nb) ? bsums[t] : 0;
    sm[t] = v;
    __syncthreads();
    for (int ofs = 1; ofs < 128; ofs <<= 1) {
        int add = (t >= ofs) ? sm[t - ofs] : 0;
        __syncthreads();
        sm[t] += add;
        __syncthreads();
    }
    if (t < nb) bsums[t] = sm[t] - v;  // exclusive
}

__global__ __launch_bounds__(256) void scan3_k(const int* __restrict__ incl,
                                               const int* __restrict__ deg,
                                               const int* __restrict__ bsumsx,
                                               int* __restrict__ offs, int n) {
    int i = blockIdx.x * 256 + threadIdx.x;
    if (i < n) offs[i] = bsumsx[i >> 9] + incl[i] - deg[i];
}

__global__ __launch_bounds__(256) void scatter_k(const int* __restrict__ src,
                                                 const int* __restrict__ dst, int E,
                                                 const int* __restrict__ offs,
                                                 int* __restrict__ cursor,
                                                 int* __restrict__ ssrc) {
    int e = blockIdx.x * 256 + threadIdx.x;
    if (e < E) {
        int d = dst[e];
        int pos = offs[d] + atomicAdd(&cursor[d], 1);
        ssrc[pos] = src[e];
    }
}

// ---------------------------------------------------------------------------
// GEMM: out = A[n,K] * W[K,M].  BM=128 x M block tile, BK=32.
// LDS 35/27 KB -> 4-5 blocks/CU (vs 3 at the old 50KB).  Each thread:
// TM=M/8 rows x 4 cols = 64/32 FMA per k-step vs 17/9 LDS reads.
// Epilogue: optional fp32 C, bf16 Cb (for the agg gather), fused el/er.
// ---------------------------------------------------------------------------
template <int K, int M>
__global__ __launch_bounds__(256, 4) void gemm_t(
    const float* __restrict__ A, const float* __restrict__ W,
    float* __restrict__ C, ushort* __restrict__ Cb, int nrows,
    const float* __restrict__ al, const float* __restrict__ ar,
    float* __restrict__ el, float* __restrict__ er) {
    constexpr int BM = 128, BK = 32;
    constexpr int AP = BK + 4;       // padded A row stride (words)
    constexpr int WP = M + 4;        // padded W row stride (words)
    constexpr int NCG = M / 4;       // col groups (32 / 16)
    constexpr int TM = M / 8;        // rows per thread (16 / 8)
    __shared__ float As[BM * AP];
    __shared__ float Ws[BK * WP];
    const int tid = threadIdx.x;
    const int row0 = blockIdx.x * BM;
    const int col_t = tid % NCG;
    const int row_t = tid / NCG;
    const int col4 = col_t << 2;

    float4 acc[TM];
#pragma unroll
    for (int i = 0; i < TM; ++i) acc[i] = make_float4(0.f, 0.f, 0.f, 0.f);

    for (int kt = 0; kt < K / BK; ++kt) {
        const int k0 = kt * BK;
        // A tile: 128 rows x 32 k = 1024 float4, 4 per thread
#pragma unroll
        for (int t = 0; t < 4; ++t) {
            int idx = tid + t * 256;
            int r = idx >> 3;            // 8 float4 per row
            int kq = (idx & 7) << 2;
            float4 v = make_float4(0.f, 0.f, 0.f, 0.f);
            if (row0 + r < nrows)
                v = *(const float4*)&A[(size_t)(row0 + r) * K + k0 + kq];
            *(float4*)&As[r * AP + kq] = v;
        }
        // W tile: 32 k x M
#pragma unroll
        for (int t = 0; t < M / 32; ++t) {
            int idx = tid + t * 256;
            int kk = idx / NCG;
            int mq = (idx % NCG) << 2;
            *(float4*)&Ws[kk * WP + mq] =
                *(const float4*)&W[(size_t)(k0 + kk) * M + mq];
        }
        __syncthreads();
#pragma unroll 4
        for (int k = 0; k < BK; ++k) {
            float4 wv = *(const float4*)&Ws[k * WP + col4];
            float av[TM];
#pragma unroll
            for (int i = 0; i < TM; ++i)
                av[i] = As[(row_t * TM + i) * AP + k];
#pragma unroll
            for (int i = 0; i < TM; ++i) {
                acc[i].x += av[i] * wv.x;
                acc[i].y += av[i] * wv.y;
                acc[i].z += av[i] * wv.z;
                acc[i].w += av[i] * wv.w;
            }
        }
        __syncthreads();
    }
#pragma unroll
    for (int i = 0; i < TM; ++i) {
        int row = row0 + row_t * TM + i;
        if (row < nrows) {
            if (C)
                *(float4*)&C[(size_t)row * M + col4] = acc[i];
            if (Cb) {
                uint b01 = f2bf(acc[i].x) | (f2bf(acc[i].y) << 16);
                uint b23 = f2bf(acc[i].z) | (f2bf(acc[i].w) << 16);
                *(uint2*)&Cb[(size_t)row * M + col4] = make_uint2(b01, b23);
            }
        }
    }
    // fused el/er epilogue
    if (al != nullptr) {
        constexpr int PS = NCG + 1;
        float* pel = As;   // 128*PS <= BM*AP  (33<=36 / 17<=36)
        float* per_ = Ws;  // 128*PS <= BK*WP  (128*33=4224<=4224 / 2176<=2176)
        float a0 = al[col4], a1 = al[col4 + 1], a2 = al[col4 + 2], a3 = al[col4 + 3];
        float r0 = ar[col4], r1 = ar[col4 + 1], r2 = ar[col4 + 2], r3 = ar[col4 + 3];
#pragma unroll
        for (int i = 0; i < TM; ++i) {
            int lr = row_t * TM + i;
            pel[lr * PS + col_t] =
                acc[i].x * a0 + acc[i].y * a1 + acc[i].z * a2 + acc[i].w * a3;
            per_[lr * PS + col_t] =
                acc[i].x * r0 + acc[i].y * r1 + acc[i].z * r2 + acc[i].w * r3;
        }
        __syncthreads();
        // 128 rows x 2 heads x {el,er}: thread -> (row, el|er), loop heads
        int row = tid >> 1;
        int iser = tid & 1;
        const float* p = iser ? per_ : pel;
        float* dstp = iser ? er : el;
        int grow = row0 + row;
        if (grow < nrows) {
#pragma unroll
            for (int hh = 0; hh < 2; ++hh) {
                float sum = 0.f;
#pragma unroll
                for (int g = 0; g < NCG / 2; ++g)
                    sum += p[row * PS + hh * (NCG / 2) + g];
                dstp[grow * 2 + hh] = sum;
            }
        }
    }
}

// ---------------------------------------------------------------------------
// Aggregation, bf16 gather: one wave per node (both heads).  Row = 2*D bf16
// = CH uint4 chunks (16 for D=64, 8 for D=32); ES = 64/CH edges per wave
// iteration (1KB per load).  Softmax fast path (deg<=64): scores held in
// registers, two butterfly reduces, no re-exp.  Weights/src broadcast via
// shuffles; fp32 accumulate; fused bias/residual/ELU/head-mean epilogue.
// ---------------------------------------------------------------------------
template <int D, bool MEAN_HEADS>
__global__ __launch_bounds__(256) void agg_b(
    const int* __restrict__ ssrc, const int* __restrict__ offs,
    const int* __restrict__ deg, const ushort* __restrict__ hb,
    const float* __restrict__ el, const float* __restrict__ er,
    const float* __restrict__ bias, const float* __restrict__ res,
    float* __restrict__ out, int act, int n) {
    constexpr int F = 2 * D;      // feats per row
    constexpr int CH = F / 8;     // uint4 chunks per row
    constexpr int ES = 64 / CH;   // edges per wave iteration
    const int wid = threadIdx.x >> 6;
    const int lane = threadIdx.x & 63;
    const int node = blockIdx.x * 4 + wid;
    if (node >= n) return;
    const int off = offs[node];
    const int dg = deg[node];
    const float2 ern = *(const float2*)&er[node * 2];

    float m0, m1, is0, is1;
    float w0r = 0.f, w1r = 0.f;
    int sidx_r = 0;
    const bool small = (dg <= 64);
    if (small) {
        float a = -INFINITY, b = -INFINITY;
        if (lane < dg) {
            sidx_r = ssrc[off + lane];
            float2 ev = *(const float2*)&el[sidx_r * 2];
            a = ev.x + ern.x; a = a >= 0.f ? a : 0.2f * a;
            b = ev.y + ern.y; b = b >= 0.f ? b : 0.2f * b;
        }
        m0 = a; m1 = b;
        for (int o = 32; o; o >>= 1) {
            m0 = fmaxf(m0, __shfl_xor(m0, o));
            m1 = fmaxf(m1, __shfl_xor(m1, o));
        }
        float p0 = (lane < dg) ? __expf(a - m0) : 0.f;
        float p1 = (lane < dg) ? __expf(b - m1) : 0.f;
        float s0 = p0, s1 = p1;
        for (int o = 32; o; o >>= 1) {
            s0 += __shfl_xor(s0, o);
            s1 += __shfl_xor(s1, o);
        }
        is0 = s0 > 0.f ? 1.f / s0 : 0.f;
        is1 = s1 > 0.f ? 1.f / s1 : 0.f;
        w0r = p0 * is0;
        w1r = p1 * is1;
    } else {  // rare: deg > 64, online softmax
        float s0 = 0.f, s1 = 0.f;
        m0 = -INFINITY; m1 = -INFINITY;
        for (int k = lane; k < dg; k += 64) {
            int sidx = ssrc[off + k];
            float2 ev = *(const float2*)&el[sidx * 2];
            float a = ev.x + ern.x; a = a >= 0.f ? a : 0.2f * a;
            float b = ev.y + ern.y; b = b >= 0.f ? b : 0.2f * b;
            float nm = fmaxf(m0, a);
            s0 = s0 * __expf(m0 - nm) + __expf(a - nm); m0 = nm;
            nm = fmaxf(m1, b);
            s1 = s1 * __expf(m1 - nm) + __expf(b - nm); m1 = nm;
        }
        for (int o = 32; o; o >>= 1) {
            float om = __shfl_xor(m0, o), os = __shfl_xor(s0, o);
            float nm = fmaxf(m0, om);
            s0 = (nm == -INFINITY) ? 0.f : s0 * __expf(m0 - nm) + os * __expf(om - nm);
            m0 = nm;
            om = __shfl_xor(m1, o); os = __shfl_xor(s1, o);
            nm = fmaxf(m1, om);
            s1 = (nm == -INFINITY) ? 0.f : s1 * __expf(m1 - nm) + os * __expf(om - nm);
            m1 = nm;
        }
        is0 = s0 > 0.f ? 1.f / s0 : 0.f;
        is1 = s1 > 0.f ? 1.f / s1 : 0.f;
    }

    const int c = lane & (CH - 1);     // chunk within row
    const int es = lane / CH;          // edge slot
    const bool head1 = (c >= CH / 2);  // chunk's head
    const uint4* __restrict__ hp = (const uint4*)hb;
    float acc[8];
#pragma unroll
    for (int i = 0; i < 8; ++i) acc[i] = 0.f;

    for (int c0 = 0; c0 < dg; c0 += 64) {
        float w0, w1;
        int sidx;
        if (small) {
            sidx = sidx_r; w0 = w0r; w1 = w1r;
        } else {
            int k = c0 + lane;
            if (k < dg) {
                sidx = ssrc[off + k];
                float2 ev = *(const float2*)&el[sidx * 2];
                float a = ev.x + ern.x; a = a >= 0.f ? a : 0.2f * a;
                float b = ev.y + ern.y; b = b >= 0.f ? b : 0.2f * b;
                w0 = __expf(a - m0) * is0;
                w1 = __expf(b - m1) * is1;
            } else {
                sidx = 0; w0 = 0.f; w1 = 0.f;
            }
        }
        const int cnt = min(64, dg - c0);
        for (int p = 0; p < cnt; p += ES) {
            int j = p + es;
            int jc = (j < cnt) ? j : 0;
            int sj = __shfl(sidx, jc);
            float wa = __shfl(w0, jc);
            float wb = __shfl(w1, jc);
            float wj = (j < cnt) ? (head1 ? wb : wa) : 0.f;
            uint4 q = hp[(size_t)sj * CH + c];
            acc[0] += wj * __uint_as_float(q.x << 16);
            acc[1] += wj * __uint_as_float(q.x & 0xffff0000u);
            acc[2] += wj * __uint_as_float(q.y << 16);
            acc[3] += wj * __uint_as_float(q.y & 0xffff0000u);
            acc[4] += wj * __uint_as_float(q.z << 16);
            acc[5] += wj * __uint_as_float(q.z & 0xffff0000u);
            acc[6] += wj * __uint_as_float(q.w << 16);
            acc[7] += wj * __uint_as_float(q.w & 0xffff0000u);
        }
    }

    // combine edge-slot partials
#pragma unroll
    for (int o = CH; o < 64; o <<= 1) {
#pragma unroll
        for (int i = 0; i < 8; ++i) acc[i] += __shfl_xor(acc[i], o);
    }

    // epilogue
    const int f0 = c * 8;
    float4 b0v = *(const float4*)&bias[f0];
    float4 b1v = *(const float4*)&bias[f0 + 4];
    float vv[8] = {acc[0] + b0v.x, acc[1] + b0v.y, acc[2] + b0v.z, acc[3] + b0v.w,
                   acc[4] + b1v.x, acc[5] + b1v.y, acc[6] + b1v.z, acc[7] + b1v.w};
    if (res) {
        float4 r0v = *(const float4*)&res[(size_t)node * F + f0];
        float4 r1v = *(const float4*)&res[(size_t)node * F + f0 + 4];
        vv[0] += r0v.x; vv[1] += r0v.y; vv[2] += r0v.z; vv[3] += r0v.w;
        vv[4] += r1v.x; vv[5] += r1v.y; vv[6] += r1v.z; vv[7] += r1v.w;
    }
    if (act) {
#pragma unroll
        for (int i = 0; i < 8; ++i)
            vv[i] = vv[i] > 0.f ? vv[i] : __expf(vv[i]) - 1.f;
    }
    if (MEAN_HEADS) {
        float ov[8];
#pragma unroll
        for (int i = 0; i < 8; ++i) ov[i] = __shfl_xor(vv[i], CH / 2);
        if (es == 0 && c < CH / 2) {
            float4 u0 = make_float4(0.5f * (vv[0] + ov[0]), 0.5f * (vv[1] + ov[1]),
                                    0.5f * (vv[2] + ov[2]), 0.5f * (vv[3] + ov[3]));
            float4 u1 = make_float4(0.5f * (vv[4] + ov[4]), 0.5f * (vv[5] + ov[5]),
                                    0.5f * (vv[6] + ov[6]), 0.5f * (vv[7] + ov[7]));
            *(float4*)&out[(size_t)node * D + f0] = u0;
            *(float4*)&out[(size_t)node * D + f0 + 4] = u1;
        }
    } else {
        if (es == 0) {
            *(float4*)&out[(size_t)node * F + f0] =
                make_float4(vv[0], vv[1], vv[2], vv[3]);
            *(float4*)&out[(size_t)node * F + f0 + 4] =
                make_float4(vv[4], vv[5], vv[6], vv[7]);
        }
    }
}

// ---------------------------------------------------------------------------

extern "C" void kernel_launch(void* const* d_in, const int* in_sizes, int n_in,
                              void* d_out, int out_size, void* d_ws, size_t ws_size,
                              hipStream_t stream) {
    const float* x     = (const float*)d_in[0];
    const int*   esrc  = (const int*)d_in[1];
    const int*   edst  = (const int*)d_in[2];
    const float* W0    = (const float*)d_in[3];
    const float* al0   = (const float*)d_in[4];
    const float* ar0   = (const float*)d_in[5];
    const float* b0    = (const float*)d_in[6];
    const float* W1    = (const float*)d_in[7];
    const float* al1   = (const float*)d_in[8];
    const float* ar1   = (const float*)d_in[9];
    const float* b1    = (const float*)d_in[10];
    const float* W2    = (const float*)d_in[11];
    const float* al2   = (const float*)d_in[12];
    const float* ar2   = (const float*)d_in[13];
    const float* b2    = (const float*)d_in[14];
    const float* Wres2 = (const float*)d_in[15];

    const int N = in_sizes[0] / 256;  // 50000
    const int E = in_sizes[1];        // 800000

    // workspace layout
    float* ws = (float*)d_ws;
    float* A    = ws;                       // [N,128] agg0 out / L1 gemm in
    float* B    = A + (size_t)N * 128;      // [N,128] agg1 out / L2 gemm in
    float* hres = B + (size_t)N * 128;      // [N,64]  L2 projected residual
    float* el   = hres + (size_t)N * 64;    // [N,2]
    float* er   = el + (size_t)N * 2;       // [N,2]
    int* deg    = (int*)(er + (size_t)N * 2);
    int* offs   = deg + N;
    int* cursor = offs + N;
    int* incl   = cursor + N;
    int* bsums  = incl + N;                 // 256 ints
    int* ssrc   = bsums + 256;              // [E]
    ushort* Hb  = (ushort*)(ssrc + E);      // [N,128] bf16 h for gathers

    // ---- CSR-by-destination build ----
    hipMemsetAsync(deg, 0, (size_t)N * sizeof(int), stream);
    hipMemsetAsync(cursor, 0, (size_t)N * sizeof(int), stream);
    hist_k<<<(E + 255) / 256, 256, 0, stream>>>(edst, E, deg);
    int nb = (N + 511) / 512;  // 98 <= 128
    scan1_k<<<nb, 512, 0, stream>>>(deg, N, incl, bsums);
    scan2_k<<<1, 128, 0, stream>>>(bsums, nb);
    scan3_k<<<(N + 255) / 256, 256, 0, stream>>>(incl, deg, bsums, offs, N);
    scatter_k<<<(E + 255) / 256, 256, 0, stream>>>(esrc, edst, E, offs, cursor, ssrc);

    int gblk = (N + 127) / 128;  // 391
    int ablk = (N + 3) / 4;      // wave per node

    // ---- Layer 0: IN=256 -> [N,2,64], ELU ----
    gemm_t<256, 128><<<gblk, 256, 0, stream>>>(x, W0, nullptr, Hb, N,
                                               al0, ar0, el, er);
    agg_b<64, false><<<ablk, 256, 0, stream>>>(ssrc, offs, deg, Hb, el, er, b0,
                                               nullptr, A, 1, N);

    // ---- Layer 1: 128 -> [N,2,64], identity residual, ELU ----
    gemm_t<128, 128><<<gblk, 256, 0, stream>>>(A, W1, nullptr, Hb, N,
                                               al1, ar1, el, er);
    agg_b<64, false><<<ablk, 256, 0, stream>>>(ssrc, offs, deg, Hb, el, er, b1,
                                               A, B, 1, N);

    // ---- Layer 2: 128 -> [N,2,32], projected residual, head-mean ----
    gemm_t<128, 64><<<gblk, 256, 0, stream>>>(B, W2, nullptr, Hb, N,
                                              al2, ar2, el, er);
    gemm_t<128, 64><<<gblk, 256, 0, stream>>>(B, Wres2, hres, nullptr, N,
                                              nullptr, nullptr, nullptr, nullptr);
    agg_b<32, true><<<ablk, 256, 0, stream>>>(ssrc, offs, deg, Hb, el, er, b2,
                                              hres, (float*)d_out, 0, N);
}

// Round 6
// 446.996 us; speedup vs baseline: 2.6790x; 2.6790x over previous
//
#include <hip/hip_runtime.h>
#include <math.h>

// ---------------------------------------------------------------------------
// GAT, 3 layers, N=50000, E=800000, H=2 heads, D=64/64/32.
// CSR-by-dst per launch; BM=64/BK=32 register-tiled fp32 GEMM (TM=8, ~68
// VGPR, 26KB LDS -> 6 blocks/CU) with fused el/er + bf16-h epilogue;
// wave-per-node aggregate gathering bf16 rows (uint4 lanes).
// ---------------------------------------------------------------------------

typedef unsigned int uint;
typedef unsigned short ushort;

__device__ inline uint f2bf(float f) {  // fp32 -> bf16 bits, RNE
    uint u = __float_as_uint(f);
    return (u + 0x7fffu + ((u >> 16) & 1u)) >> 16;
}

__global__ __launch_bounds__(256) void hist_k(const int* __restrict__ dst, int E,
                                              int* __restrict__ deg) {
    int e = blockIdx.x * 256 + threadIdx.x;
    if (e < E) atomicAdd(&deg[dst[e]], 1);
}

__global__ __launch_bounds__(512) void scan1_k(const int* __restrict__ deg, int n,
                                               int* __restrict__ incl,
                                               int* __restrict__ bsums) {
    __shared__ int sm[512];
    int t = threadIdx.x;
    int i = blockIdx.x * 512 + t;
    int v = (i < n) ? deg[i] : 0;
    sm[t] = v;
    __syncthreads();
    for (int ofs = 1; ofs < 512; ofs <<= 1) {
        int add = (t >= ofs) ? sm[t - ofs] : 0;
        __syncthreads();
        sm[t] += add;
        __syncthreads();
    }
    if (i < n) incl[i] = sm[t];
    if (t == 511) bsums[blockIdx.x] = sm[511];
}

__global__ __launch_bounds__(128) void scan2_k(int* __restrict__ bsums, int nb) {
    __shared__ int sm[128];
    int t = threadIdx.x;
    int v = (t < nb) ? bsums[t] : 0;
    sm[t] = v;
    __syncthreads();
    for (int ofs = 1; ofs < 128; ofs <<= 1) {
        int add = (t >= ofs) ? sm[t - ofs] : 0;
        __syncthreads();
        sm[t] += add;
        __syncthreads();
    }
    if (t < nb) bsums[t] = sm[t] - v;  // exclusive
}

__global__ __launch_bounds__(256) void scan3_k(const int* __restrict__ incl,
                                               const int* __restrict__ deg,
                                               const int* __restrict__ bsumsx,
                                               int* __restrict__ offs, int n) {
    int i = blockIdx.x * 256 + threadIdx.x;
    if (i < n) offs[i] = bsumsx[i >> 9] + incl[i] - deg[i];
}

__global__ __launch_bounds__(256) void scatter_k(const int* __restrict__ src,
                                                 const int* __restrict__ dst, int E,
                                                 const int* __restrict__ offs,
                                                 int* __restrict__ cursor,
                                                 int* __restrict__ ssrc) {
    int e = blockIdx.x * 256 + threadIdx.x;
    if (e < E) {
        int d = dst[e];
        int pos = offs[d] + atomicAdd(&cursor[d], 1);
        ssrc[pos] = src[e];
    }
}

// ---------------------------------------------------------------------------
// GEMM: out = A[n,K] * W[K,M].  BM=64 x M tile, BK=32.
// LDS 26KB (M=128) / 18KB (M=64).  Each thread: TM=8 rows x 4 cols = 32 FMA
// per k-step vs 9 LDS reads.  acc = 32 VGPR -> no spill, no launch_bounds cap.
// Epilogue: optional fp32 C, bf16 Cb (for agg gather), fused el/er.
// ---------------------------------------------------------------------------
template <int K, int M>
__global__ __launch_bounds__(256) void gemm_t(
    const float* __restrict__ A, const float* __restrict__ W,
    float* __restrict__ C, ushort* __restrict__ Cb, int nrows,
    const float* __restrict__ al, const float* __restrict__ ar,
    float* __restrict__ el, float* __restrict__ er) {
    constexpr int BM = 64, BK = 32;
    constexpr int AP = BK + 4;       // padded A row stride (words)
    constexpr int WP = M + 4;        // padded W row stride (words)
    constexpr int NCG = M / 4;       // col groups (32 / 16)
    constexpr int TM = 8;            // rows per thread (256 threads = NCG*8)
    __shared__ float As[BM * AP];
    __shared__ float Ws[BK * WP];
    const int tid = threadIdx.x;
    const int row0 = blockIdx.x * BM;
    const int col_t = tid % NCG;
    const int row_t = tid / NCG;     // [0, 256/NCG) = [0,8) or [0,16)
    const int col4 = col_t << 2;
    // for M=64 there are 16 row groups of 4 rows; for M=128, 8 groups of 8
    constexpr int RG = 256 / NCG;    // row groups
    constexpr int RPT = BM / RG;     // rows per thread (8 for M=128, 4 for M=64)

    float4 acc[RPT];
#pragma unroll
    for (int i = 0; i < RPT; ++i) acc[i] = make_float4(0.f, 0.f, 0.f, 0.f);

    for (int kt = 0; kt < K / BK; ++kt) {
        const int k0 = kt * BK;
        // A tile: 64 rows x 32 k = 512 float4, 2 per thread
#pragma unroll
        for (int t = 0; t < 2; ++t) {
            int idx = tid + t * 256;
            int r = idx >> 3;            // 8 float4 per row
            int kq = (idx & 7) << 2;
            float4 v = make_float4(0.f, 0.f, 0.f, 0.f);
            if (row0 + r < nrows)
                v = *(const float4*)&A[(size_t)(row0 + r) * K + k0 + kq];
            *(float4*)&As[r * AP + kq] = v;
        }
        // W tile: 32 k x M
#pragma unroll
        for (int t = 0; t < M / 32; ++t) {
            int idx = tid + t * 256;
            int kk = idx / NCG;
            int mq = (idx % NCG) << 2;
            *(float4*)&Ws[kk * WP + mq] =
                *(const float4*)&W[(size_t)(k0 + kk) * M + mq];
        }
        __syncthreads();
#pragma unroll 4
        for (int k = 0; k < BK; ++k) {
            float4 wv = *(const float4*)&Ws[k * WP + col4];
            float av[RPT];
#pragma unroll
            for (int i = 0; i < RPT; ++i)
                av[i] = As[(row_t * RPT + i) * AP + k];
#pragma unroll
            for (int i = 0; i < RPT; ++i) {
                acc[i].x += av[i] * wv.x;
                acc[i].y += av[i] * wv.y;
                acc[i].z += av[i] * wv.z;
                acc[i].w += av[i] * wv.w;
            }
        }
        __syncthreads();
    }
#pragma unroll
    for (int i = 0; i < RPT; ++i) {
        int row = row0 + row_t * RPT + i;
        if (row < nrows) {
            if (C)
                *(float4*)&C[(size_t)row * M + col4] = acc[i];
            if (Cb) {
                uint b01 = f2bf(acc[i].x) | (f2bf(acc[i].y) << 16);
                uint b23 = f2bf(acc[i].z) | (f2bf(acc[i].w) << 16);
                *(uint2*)&Cb[(size_t)row * M + col4] = make_uint2(b01, b23);
            }
        }
    }
    // fused el/er epilogue
    if (al != nullptr) {
        constexpr int PS = NCG + 1;
        float* pel = As;   // 64*PS <= BM*AP (2112<=2304 / 1088<=2304)
        float* per_ = Ws;  // 64*PS <= BK*WP (2112<=4224 / 1088<=2176)
        float a0 = al[col4], a1 = al[col4 + 1], a2 = al[col4 + 2], a3 = al[col4 + 3];
        float r0 = ar[col4], r1 = ar[col4 + 1], r2 = ar[col4 + 2], r3 = ar[col4 + 3];
#pragma unroll
        for (int i = 0; i < RPT; ++i) {
            int lr = row_t * RPT + i;
            pel[lr * PS + col_t] =
                acc[i].x * a0 + acc[i].y * a1 + acc[i].z * a2 + acc[i].w * a3;
            per_[lr * PS + col_t] =
                acc[i].x * r0 + acc[i].y * r1 + acc[i].z * r2 + acc[i].w * r3;
        }
        __syncthreads();
        // 64 rows x {head0,head1} x {el,er} = 256 outputs, one per thread
        int row = tid >> 2;
        int hh = tid & 1;
        int iser = (tid >> 1) & 1;
        const float* p = iser ? per_ : pel;
        float sum = 0.f;
#pragma unroll
        for (int g = 0; g < NCG / 2; ++g)
            sum += p[row * PS + hh * (NCG / 2) + g];
        int grow = row0 + row;
        if (grow < nrows) {
            float* dstp = iser ? er : el;
            dstp[grow * 2 + hh] = sum;
        }
    }
}

// ---------------------------------------------------------------------------
// Aggregation, bf16 gather: one wave per node (both heads).  Row = 2*D bf16
// = CH uint4 chunks (16 for D=64, 8 for D=32); ES = 64/CH edges per wave
// iteration (1KB per load).  Softmax fast path (deg<=64): scores held in
// registers.  Weights/src broadcast via shuffles; fp32 accumulate; fused
// bias/residual/ELU/head-mean epilogue.
// ---------------------------------------------------------------------------
template <int D, bool MEAN_HEADS>
__global__ __launch_bounds__(256) void agg_b(
    const int* __restrict__ ssrc, const int* __restrict__ offs,
    const int* __restrict__ deg, const ushort* __restrict__ hb,
    const float* __restrict__ el, const float* __restrict__ er,
    const float* __restrict__ bias, const float* __restrict__ res,
    float* __restrict__ out, int act, int n) {
    constexpr int F = 2 * D;      // feats per row
    constexpr int CH = F / 8;     // uint4 chunks per row
    constexpr int ES = 64 / CH;   // edges per wave iteration
    const int wid = threadIdx.x >> 6;
    const int lane = threadIdx.x & 63;
    const int node = blockIdx.x * 4 + wid;
    if (node >= n) return;
    const int off = offs[node];
    const int dg = deg[node];
    const float2 ern = *(const float2*)&er[node * 2];

    float m0, m1, is0, is1;
    float w0r = 0.f, w1r = 0.f;
    int sidx_r = 0;
    const bool small = (dg <= 64);
    if (small) {
        float a = -INFINITY, b = -INFINITY;
        if (lane < dg) {
            sidx_r = ssrc[off + lane];
            float2 ev = *(const float2*)&el[sidx_r * 2];
            a = ev.x + ern.x; a = a >= 0.f ? a : 0.2f * a;
            b = ev.y + ern.y; b = b >= 0.f ? b : 0.2f * b;
        }
        m0 = a; m1 = b;
        for (int o = 32; o; o >>= 1) {
            m0 = fmaxf(m0, __shfl_xor(m0, o));
            m1 = fmaxf(m1, __shfl_xor(m1, o));
        }
        float p0 = (lane < dg) ? __expf(a - m0) : 0.f;
        float p1 = (lane < dg) ? __expf(b - m1) : 0.f;
        float s0 = p0, s1 = p1;
        for (int o = 32; o; o >>= 1) {
            s0 += __shfl_xor(s0, o);
            s1 += __shfl_xor(s1, o);
        }
        is0 = s0 > 0.f ? 1.f / s0 : 0.f;
        is1 = s1 > 0.f ? 1.f / s1 : 0.f;
        w0r = p0 * is0;
        w1r = p1 * is1;
    } else {  // rare: deg > 64, online softmax
        float s0 = 0.f, s1 = 0.f;
        m0 = -INFINITY; m1 = -INFINITY;
        for (int k = lane; k < dg; k += 64) {
            int sidx = ssrc[off + k];
            float2 ev = *(const float2*)&el[sidx * 2];
            float a = ev.x + ern.x; a = a >= 0.f ? a : 0.2f * a;
            float b = ev.y + ern.y; b = b >= 0.f ? b : 0.2f * b;
            float nm = fmaxf(m0, a);
            s0 = s0 * __expf(m0 - nm) + __expf(a - nm); m0 = nm;
            nm = fmaxf(m1, b);
            s1 = s1 * __expf(m1 - nm) + __expf(b - nm); m1 = nm;
        }
        for (int o = 32; o; o >>= 1) {
            float om = __shfl_xor(m0, o), os = __shfl_xor(s0, o);
            float nm = fmaxf(m0, om);
            s0 = (nm == -INFINITY) ? 0.f : s0 * __expf(m0 - nm) + os * __expf(om - nm);
            m0 = nm;
            om = __shfl_xor(m1, o); os = __shfl_xor(s1, o);
            nm = fmaxf(m1, om);
            s1 = (nm == -INFINITY) ? 0.f : s1 * __expf(m1 - nm) + os * __expf(om - nm);
            m1 = nm;
        }
        is0 = s0 > 0.f ? 1.f / s0 : 0.f;
        is1 = s1 > 0.f ? 1.f / s1 : 0.f;
    }

    const int c = lane & (CH - 1);     // chunk within row
    const int es = lane / CH;          // edge slot
    const bool head1 = (c >= CH / 2);  // chunk's head
    const uint4* __restrict__ hp = (const uint4*)hb;
    float acc[8];
#pragma unroll
    for (int i = 0; i < 8; ++i) acc[i] = 0.f;

    for (int c0 = 0; c0 < dg; c0 += 64) {
        float w0, w1;
        int sidx;
        if (small) {
            sidx = sidx_r; w0 = w0r; w1 = w1r;
        } else {
            int k = c0 + lane;
            if (k < dg) {
                sidx = ssrc[off + k];
                float2 ev = *(const float2*)&el[sidx * 2];
                float a = ev.x + ern.x; a = a >= 0.f ? a : 0.2f * a;
                float b = ev.y + ern.y; b = b >= 0.f ? b : 0.2f * b;
                w0 = __expf(a - m0) * is0;
                w1 = __expf(b - m1) * is1;
            } else {
                sidx = 0; w0 = 0.f; w1 = 0.f;
            }
        }
        const int cnt = min(64, dg - c0);
        for (int p = 0; p < cnt; p += ES) {
            int j = p + es;
            int jc = (j < cnt) ? j : 0;
            int sj = __shfl(sidx, jc);
            float wa = __shfl(w0, jc);
            float wb = __shfl(w1, jc);
            float wj = (j < cnt) ? (head1 ? wb : wa) : 0.f;
            uint4 q = hp[(size_t)sj * CH + c];
            acc[0] += wj * __uint_as_float(q.x << 16);
            acc[1] += wj * __uint_as_float(q.x & 0xffff0000u);
            acc[2] += wj * __uint_as_float(q.y << 16);
            acc[3] += wj * __uint_as_float(q.y & 0xffff0000u);
            acc[4] += wj * __uint_as_float(q.z << 16);
            acc[5] += wj * __uint_as_float(q.z & 0xffff0000u);
            acc[6] += wj * __uint_as_float(q.w << 16);
            acc[7] += wj * __uint_as_float(q.w & 0xffff0000u);
        }
    }

    // combine edge-slot partials
#pragma unroll
    for (int o = CH; o < 64; o <<= 1) {
#pragma unroll
        for (int i = 0; i < 8; ++i) acc[i] += __shfl_xor(acc[i], o);
    }

    // epilogue
    const int f0 = c * 8;
    float4 b0v = *(const float4*)&bias[f0];
    float4 b1v = *(const float4*)&bias[f0 + 4];
    float vv[8] = {acc[0] + b0v.x, acc[1] + b0v.y, acc[2] + b0v.z, acc[3] + b0v.w,
                   acc[4] + b1v.x, acc[5] + b1v.y, acc[6] + b1v.z, acc[7] + b1v.w};
    if (res) {
        float4 r0v = *(const float4*)&res[(size_t)node * F + f0];
        float4 r1v = *(const float4*)&res[(size_t)node * F + f0 + 4];
        vv[0] += r0v.x; vv[1] += r0v.y; vv[2] += r0v.z; vv[3] += r0v.w;
        vv[4] += r1v.x; vv[5] += r1v.y; vv[6] += r1v.z; vv[7] += r1v.w;
    }
    if (act) {
#pragma unroll
        for (int i = 0; i < 8; ++i)
            vv[i] = vv[i] > 0.f ? vv[i] : __expf(vv[i]) - 1.f;
    }
    if (MEAN_HEADS) {
        float ov[8];
#pragma unroll
        for (int i = 0; i < 8; ++i) ov[i] = __shfl_xor(vv[i], CH / 2);
        if (es == 0 && c < CH / 2) {
            float4 u0 = make_float4(0.5f * (vv[0] + ov[0]), 0.5f * (vv[1] + ov[1]),
                                    0.5f * (vv[2] + ov[2]), 0.5f * (vv[3] + ov[3]));
            float4 u1 = make_float4(0.5f * (vv[4] + ov[4]), 0.5f * (vv[5] + ov[5]),
                                    0.5f * (vv[6] + ov[6]), 0.5f * (vv[7] + ov[7]));
            *(float4*)&out[(size_t)node * D + f0] = u0;
            *(float4*)&out[(size_t)node * D + f0 + 4] = u1;
        }
    } else {
        if (es == 0) {
            *(float4*)&out[(size_t)node * F + f0] =
                make_float4(vv[0], vv[1], vv[2], vv[3]);
            *(float4*)&out[(size_t)node * F + f0 + 4] =
                make_float4(vv[4], vv[5], vv[6], vv[7]);
        }
    }
}

// ---------------------------------------------------------------------------

extern "C" void kernel_launch(void* const* d_in, const int* in_sizes, int n_in,
                              void* d_out, int out_size, void* d_ws, size_t ws_size,
                              hipStream_t stream) {
    const float* x     = (const float*)d_in[0];
    const int*   esrc  = (const int*)d_in[1];
    const int*   edst  = (const int*)d_in[2];
    const float* W0    = (const float*)d_in[3];
    const float* al0   = (const float*)d_in[4];
    const float* ar0   = (const float*)d_in[5];
    const float* b0    = (const float*)d_in[6];
    const float* W1    = (const float*)d_in[7];
    const float* al1   = (const float*)d_in[8];
    const float* ar1   = (const float*)d_in[9];
    const float* b1    = (const float*)d_in[10];
    const float* W2    = (const float*)d_in[11];
    const float* al2   = (const float*)d_in[12];
    const float* ar2   = (const float*)d_in[13];
    const float* b2    = (const float*)d_in[14];
    const float* Wres2 = (const float*)d_in[15];

    const int N = in_sizes[0] / 256;  // 50000
    const int E = in_sizes[1];        // 800000

    // workspace layout
    float* ws = (float*)d_ws;
    float* A    = ws;                       // [N,128] agg0 out / L1 gemm in
    float* B    = A + (size_t)N * 128;      // [N,128] agg1 out / L2 gemm in
    float* hres = B + (size_t)N * 128;      // [N,64]  L2 projected residual
    float* el   = hres + (size_t)N * 64;    // [N,2]
    float* er   = el + (size_t)N * 2;       // [N,2]
    int* deg    = (int*)(er + (size_t)N * 2);
    int* offs   = deg + N;
    int* cursor = offs + N;
    int* incl   = cursor + N;
    int* bsums  = incl + N;                 // 256 ints
    int* ssrc   = bsums + 256;              // [E]
    ushort* Hb  = (ushort*)(ssrc + E);      // [N,128] bf16 h for gathers

    // ---- CSR-by-destination build ----
    hipMemsetAsync(deg, 0, (size_t)N * sizeof(int), stream);
    hipMemsetAsync(cursor, 0, (size_t)N * sizeof(int), stream);
    hist_k<<<(E + 255) / 256, 256, 0, stream>>>(edst, E, deg);
    int nb = (N + 511) / 512;  // 98 <= 128
    scan1_k<<<nb, 512, 0, stream>>>(deg, N, incl, bsums);
    scan2_k<<<1, 128, 0, stream>>>(bsums, nb);
    scan3_k<<<(N + 255) / 256, 256, 0, stream>>>(incl, deg, bsums, offs, N);
    scatter_k<<<(E + 255) / 256, 256, 0, stream>>>(esrc, edst, E, offs, cursor, ssrc);

    int gblk = (N + 63) / 64;  // 782
    int ablk = (N + 3) / 4;    // wave per node

    // ---- Layer 0: IN=256 -> [N,2,64], ELU ----
    gemm_t<256, 128><<<gblk, 256, 0, stream>>>(x, W0, nullptr, Hb, N,
                                               al0, ar0, el, er);
    agg_b<64, false><<<ablk, 256, 0, stream>>>(ssrc, offs, deg, Hb, el, er, b0,
                                               nullptr, A, 1, N);

    // ---- Layer 1: 128 -> [N,2,64], identity residual, ELU ----
    gemm_t<128, 128><<<gblk, 256, 0, stream>>>(A, W1, nullptr, Hb, N,
                                               al1, ar1, el, er);
    agg_b<64, false><<<ablk, 256, 0, stream>>>(ssrc, offs, deg, Hb, el, er, b1,
                                               A, B, 1, N);

    // ---- Layer 2: 128 -> [N,2,32], projected residual, head-mean ----
    gemm_t<128, 64><<<gblk, 256, 0, stream>>>(B, W2, nullptr, Hb, N,
                                              al2, ar2, el, er);
    gemm_t<128, 64><<<gblk, 256, 0, stream>>>(B, Wres2, hres, nullptr, N,
                                              nullptr, nullptr, nullptr, nullptr);
    agg_b<32, true><<<ablk, 256, 0, stream>>>(ssrc, offs, deg, Hb, el, er, b2,
                                              hres, (float*)d_out, 0, N);
}

// Round 7
// 442.447 us; speedup vs baseline: 2.7065x; 1.0103x over previous
//
#include <hip/hip_runtime.h>
#include <math.h>

// ---------------------------------------------------------------------------
// GAT, 3 layers, N=50000, E=800000, H=2 heads, D=64/64/32.
// CSR-by-dst per launch; 64x64-tile fp32 GEMM (split-N grid = 1564 blocks,
// 6 blocks/CU) with fused el/er + bf16-h epilogue (tile == head for M=128;
// L2 fuses W2+Wres2 as two tiles); wave-per-node bf16 aggregate.
// ---------------------------------------------------------------------------

typedef unsigned int uint;
typedef unsigned short ushort;

__device__ inline uint f2bf(float f) {  // fp32 -> bf16 bits, RNE
    uint u = __float_as_uint(f);
    return (u + 0x7fffu + ((u >> 16) & 1u)) >> 16;
}

__global__ __launch_bounds__(256) void hist_k(const int* __restrict__ dst, int E,
                                              int* __restrict__ deg) {
    int e = blockIdx.x * 256 + threadIdx.x;
    if (e < E) atomicAdd(&deg[dst[e]], 1);
}

__global__ __launch_bounds__(512) void scan1_k(const int* __restrict__ deg, int n,
                                               int* __restrict__ incl,
                                               int* __restrict__ bsums) {
    __shared__ int sm[512];
    int t = threadIdx.x;
    int i = blockIdx.x * 512 + t;
    int v = (i < n) ? deg[i] : 0;
    sm[t] = v;
    __syncthreads();
    for (int ofs = 1; ofs < 512; ofs <<= 1) {
        int add = (t >= ofs) ? sm[t - ofs] : 0;
        __syncthreads();
        sm[t] += add;
        __syncthreads();
    }
    if (i < n) incl[i] = sm[t];
    if (t == 511) bsums[blockIdx.x] = sm[511];
}

__global__ __launch_bounds__(128) void scan2_k(int* __restrict__ bsums, int nb) {
    __shared__ int sm[128];
    int t = threadIdx.x;
    int v = (t < nb) ? bsums[t] : 0;
    sm[t] = v;
    __syncthreads();
    for (int ofs = 1; ofs < 128; ofs <<= 1) {
        int add = (t >= ofs) ? sm[t - ofs] : 0;
        __syncthreads();
        sm[t] += add;
        __syncthreads();
    }
    if (t < nb) bsums[t] = sm[t] - v;  // exclusive
}

__global__ __launch_bounds__(256) void scan3_k(const int* __restrict__ incl,
                                               const int* __restrict__ deg,
                                               const int* __restrict__ bsumsx,
                                               int* __restrict__ offs, int n) {
    int i = blockIdx.x * 256 + threadIdx.x;
    if (i < n) offs[i] = bsumsx[i >> 9] + incl[i] - deg[i];
}

__global__ __launch_bounds__(256) void scatter_k(const int* __restrict__ src,
                                                 const int* __restrict__ dst, int E,
                                                 const int* __restrict__ offs,
                                                 int* __restrict__ cursor,
                                                 int* __restrict__ ssrc) {
    int e = blockIdx.x * 256 + threadIdx.x;
    if (e < E) {
        int d = dst[e];
        int pos = offs[d] + atomicAdd(&cursor[d], 1);
        ssrc[pos] = src[e];
    }
}

// ---------------------------------------------------------------------------
// GEMM, 64x64 tile: C[r, 64c..64c+63] = A[r,:K] * W[:, tile cols].
// Grid = rowTiles*2 (tile = blockIdx&1).  LDS 17.9KB -> 6+ blocks/CU at the
// 1564-block grid.  Thread: 4 rows x 4 cols = 16 FMA vs 5 LDS reads/k-step;
// acc = 16 VGPR, no spill.  Ws span 64 words -> <=2-way bank alias (free).
// !TWOW: W stride 128, tile==head; writes bf16 Cb (stride 128) + el/er[head].
// TWOW (L2): tile0 = Wa (stride 64) -> Cb (stride 64) + both heads' el/er;
//            tile1 = Wb -> fp32 Cf residual.
// ---------------------------------------------------------------------------
template <int K, bool TWOW>
__global__ __launch_bounds__(256) void gemm_s(
    const float* __restrict__ A, const float* __restrict__ Wa,
    const float* __restrict__ Wb, float* __restrict__ Cf,
    ushort* __restrict__ Cb, int nrows,
    const float* __restrict__ al, const float* __restrict__ ar,
    float* __restrict__ el, float* __restrict__ er) {
    constexpr int BK = 32;
    constexpr int AP = BK + 4;   // 36
    constexpr int WP = 64 + 4;   // 68
    __shared__ float As[64 * AP];   // 2304 words
    __shared__ float Ws[BK * WP];   // 2176 words
    const int tid = threadIdx.x;
    const int tile = blockIdx.x & 1;
    const int row0 = (blockIdx.x >> 1) * 64;
    const int col_t = tid & 15;
    const int row_t = tid >> 4;      // 0..15
    const int col4 = col_t << 2;

    const int wstride = TWOW ? 64 : 128;
    const float* wbase = TWOW ? (tile ? Wb : Wa) : (Wa + tile * 64);

    float4 acc[4];
#pragma unroll
    for (int i = 0; i < 4; ++i) acc[i] = make_float4(0.f, 0.f, 0.f, 0.f);

    for (int kt = 0; kt < K / BK; ++kt) {
        const int k0 = kt * BK;
        // A tile: 64 rows x 32 k = 512 float4, 2/thread
#pragma unroll
        for (int t = 0; t < 2; ++t) {
            int idx = tid + t * 256;
            int r = idx >> 3;
            int kq = (idx & 7) << 2;
            float4 v = make_float4(0.f, 0.f, 0.f, 0.f);
            if (row0 + r < nrows)
                v = *(const float4*)&A[(size_t)(row0 + r) * K + k0 + kq];
            *(float4*)&As[r * AP + kq] = v;
        }
        // W tile: 32 k x 64 cols = 512 float4, 2/thread
#pragma unroll
        for (int t = 0; t < 2; ++t) {
            int idx = tid + t * 256;
            int kk = idx >> 4;
            int mq = (idx & 15) << 2;
            *(float4*)&Ws[kk * WP + mq] =
                *(const float4*)&wbase[(size_t)(k0 + kk) * wstride + mq];
        }
        __syncthreads();
#pragma unroll 8
        for (int k = 0; k < BK; ++k) {
            float4 wv = *(const float4*)&Ws[k * WP + col4];
            float av[4];
#pragma unroll
            for (int i = 0; i < 4; ++i)
                av[i] = As[(row_t * 4 + i) * AP + k];
#pragma unroll
            for (int i = 0; i < 4; ++i) {
                acc[i].x += av[i] * wv.x;
                acc[i].y += av[i] * wv.y;
                acc[i].z += av[i] * wv.z;
                acc[i].w += av[i] * wv.w;
            }
        }
        __syncthreads();
    }
    // store
#pragma unroll
    for (int i = 0; i < 4; ++i) {
        int row = row0 + row_t * 4 + i;
        if (row < nrows) {
            if (!TWOW || tile == 0) {
                const int cstride = TWOW ? 64 : 128;
                const int coff = TWOW ? 0 : tile * 64;
                uint b01 = f2bf(acc[i].x) | (f2bf(acc[i].y) << 16);
                uint b23 = f2bf(acc[i].z) | (f2bf(acc[i].w) << 16);
                *(uint2*)&Cb[(size_t)row * cstride + coff + col4] =
                    make_uint2(b01, b23);
            } else {
                *(float4*)&Cf[(size_t)row * 64 + col4] = acc[i];
            }
        }
    }
    // fused el/er epilogue
    if (!TWOW || tile == 0) {
        constexpr int PS = 17;
        float* pel = As;   // 64*17 = 1088 <= 2304
        float* per_ = Ws;  // 1088 <= 2176
        const int ai = (TWOW ? 0 : tile * 64) + col4;
        float a0 = al[ai], a1 = al[ai + 1], a2 = al[ai + 2], a3 = al[ai + 3];
        float r0 = ar[ai], r1 = ar[ai + 1], r2 = ar[ai + 2], r3 = ar[ai + 3];
#pragma unroll
        for (int i = 0; i < 4; ++i) {
            int lr = row_t * 4 + i;
            pel[lr * PS + col_t] =
                acc[i].x * a0 + acc[i].y * a1 + acc[i].z * a2 + acc[i].w * a3;
            per_[lr * PS + col_t] =
                acc[i].x * r0 + acc[i].y * r1 + acc[i].z * r2 + acc[i].w * r3;
        }
        __syncthreads();
        if (TWOW) {
            // 64 rows x 2 heads x {el,er} = 256 outputs
            int row = tid >> 2;
            int hh = tid & 1;
            int iser = (tid >> 1) & 1;
            const float* p = iser ? per_ : pel;
            float sum = 0.f;
#pragma unroll
            for (int g = 0; g < 8; ++g) sum += p[row * PS + hh * 8 + g];
            int grow = row0 + row;
            if (grow < nrows) {
                float* dstp = iser ? er : el;
                dstp[grow * 2 + hh] = sum;
            }
        } else {
            // 64 rows x {el,er} = 128 outputs; head = tile
            if (tid < 128) {
                int row = tid >> 1;
                int iser = tid & 1;
                const float* p = iser ? per_ : pel;
                float sum = 0.f;
#pragma unroll
                for (int g = 0; g < 16; ++g) sum += p[row * PS + g];
                int grow = row0 + row;
                if (grow < nrows) {
                    float* dstp = iser ? er : el;
                    dstp[grow * 2 + tile] = sum;
                }
            }
        }
    }
}

// ---------------------------------------------------------------------------
// Aggregation, bf16 gather: one wave per node (both heads).  Row = 2*D bf16
// = CH uint4 chunks; ES = 64/CH edges per wave iteration (1KB/load).
// Softmax fast path (deg<=64) with register-held scores; weights/src
// broadcast via shuffles; fp32 accumulate; fused epilogue.
// ---------------------------------------------------------------------------
template <int D, bool MEAN_HEADS>
__global__ __launch_bounds__(256) void agg_b(
    const int* __restrict__ ssrc, const int* __restrict__ offs,
    const int* __restrict__ deg, const ushort* __restrict__ hb,
    const float* __restrict__ el, const float* __restrict__ er,
    const float* __restrict__ bias, const float* __restrict__ res,
    float* __restrict__ out, int act, int n) {
    constexpr int F = 2 * D;      // feats per row
    constexpr int CH = F / 8;     // uint4 chunks per row
    constexpr int ES = 64 / CH;   // edges per wave iteration
    const int wid = threadIdx.x >> 6;
    const int lane = threadIdx.x & 63;
    const int node = blockIdx.x * 4 + wid;
    if (node >= n) return;
    const int off = offs[node];
    const int dg = deg[node];
    const float2 ern = *(const float2*)&er[node * 2];

    float m0, m1, is0, is1;
    float w0r = 0.f, w1r = 0.f;
    int sidx_r = 0;
    const bool small = (dg <= 64);
    if (small) {
        float a = -INFINITY, b = -INFINITY;
        if (lane < dg) {
            sidx_r = ssrc[off + lane];
            float2 ev = *(const float2*)&el[sidx_r * 2];
            a = ev.x + ern.x; a = a >= 0.f ? a : 0.2f * a;
            b = ev.y + ern.y; b = b >= 0.f ? b : 0.2f * b;
        }
        m0 = a; m1 = b;
        for (int o = 32; o; o >>= 1) {
            m0 = fmaxf(m0, __shfl_xor(m0, o));
            m1 = fmaxf(m1, __shfl_xor(m1, o));
        }
        float p0 = (lane < dg) ? __expf(a - m0) : 0.f;
        float p1 = (lane < dg) ? __expf(b - m1) : 0.f;
        float s0 = p0, s1 = p1;
        for (int o = 32; o; o >>= 1) {
            s0 += __shfl_xor(s0, o);
            s1 += __shfl_xor(s1, o);
        }
        is0 = s0 > 0.f ? 1.f / s0 : 0.f;
        is1 = s1 > 0.f ? 1.f / s1 : 0.f;
        w0r = p0 * is0;
        w1r = p1 * is1;
    } else {  // rare: deg > 64, online softmax
        float s0 = 0.f, s1 = 0.f;
        m0 = -INFINITY; m1 = -INFINITY;
        for (int k = lane; k < dg; k += 64) {
            int sidx = ssrc[off + k];
            float2 ev = *(const float2*)&el[sidx * 2];
            float a = ev.x + ern.x; a = a >= 0.f ? a : 0.2f * a;
            float b = ev.y + ern.y; b = b >= 0.f ? b : 0.2f * b;
            float nm = fmaxf(m0, a);
            s0 = s0 * __expf(m0 - nm) + __expf(a - nm); m0 = nm;
            nm = fmaxf(m1, b);
            s1 = s1 * __expf(m1 - nm) + __expf(b - nm); m1 = nm;
        }
        for (int o = 32; o; o >>= 1) {
            float om = __shfl_xor(m0, o), os = __shfl_xor(s0, o);
            float nm = fmaxf(m0, om);
            s0 = (nm == -INFINITY) ? 0.f : s0 * __expf(m0 - nm) + os * __expf(om - nm);
            m0 = nm;
            om = __shfl_xor(m1, o); os = __shfl_xor(s1, o);
            nm = fmaxf(m1, om);
            s1 = (nm == -INFINITY) ? 0.f : s1 * __expf(m1 - nm) + os * __expf(om - nm);
            m1 = nm;
        }
        is0 = s0 > 0.f ? 1.f / s0 : 0.f;
        is1 = s1 > 0.f ? 1.f / s1 : 0.f;
    }

    const int c = lane & (CH - 1);     // chunk within row
    const int es = lane / CH;          // edge slot
    const bool head1 = (c >= CH / 2);  // chunk's head
    const uint4* __restrict__ hp = (const uint4*)hb;
    float acc[8];
#pragma unroll
    for (int i = 0; i < 8; ++i) acc[i] = 0.f;

    for (int c0 = 0; c0 < dg; c0 += 64) {
        float w0, w1;
        int sidx;
        if (small) {
            sidx = sidx_r; w0 = w0r; w1 = w1r;
        } else {
            int k = c0 + lane;
            if (k < dg) {
                sidx = ssrc[off + k];
                float2 ev = *(const float2*)&el[sidx * 2];
                float a = ev.x + ern.x; a = a >= 0.f ? a : 0.2f * a;
                float b = ev.y + ern.y; b = b >= 0.f ? b : 0.2f * b;
                w0 = __expf(a - m0) * is0;
                w1 = __expf(b - m1) * is1;
            } else {
                sidx = 0; w0 = 0.f; w1 = 0.f;
            }
        }
        const int cnt = min(64, dg - c0);
        for (int p = 0; p < cnt; p += ES) {
            int j = p + es;
            int jc = (j < cnt) ? j : 0;
            int sj = __shfl(sidx, jc);
            float wa = __shfl(w0, jc);
            float wb = __shfl(w1, jc);
            float wj = (j < cnt) ? (head1 ? wb : wa) : 0.f;
            uint4 q = hp[(size_t)sj * CH + c];
            acc[0] += wj * __uint_as_float(q.x << 16);
            acc[1] += wj * __uint_as_float(q.x & 0xffff0000u);
            acc[2] += wj * __uint_as_float(q.y << 16);
            acc[3] += wj * __uint_as_float(q.y & 0xffff0000u);
            acc[4] += wj * __uint_as_float(q.z << 16);
            acc[5] += wj * __uint_as_float(q.z & 0xffff0000u);
            acc[6] += wj * __uint_as_float(q.w << 16);
            acc[7] += wj * __uint_as_float(q.w & 0xffff0000u);
        }
    }

    // combine edge-slot partials
#pragma unroll
    for (int o = CH; o < 64; o <<= 1) {
#pragma unroll
        for (int i = 0; i < 8; ++i) acc[i] += __shfl_xor(acc[i], o);
    }

    // epilogue
    const int f0 = c * 8;
    float4 b0v = *(const float4*)&bias[f0];
    float4 b1v = *(const float4*)&bias[f0 + 4];
    float vv[8] = {acc[0] + b0v.x, acc[1] + b0v.y, acc[2] + b0v.z, acc[3] + b0v.w,
                   acc[4] + b1v.x, acc[5] + b1v.y, acc[6] + b1v.z, acc[7] + b1v.w};
    if (res) {
        float4 r0v = *(const float4*)&res[(size_t)node * F + f0];
        float4 r1v = *(const float4*)&res[(size_t)node * F + f0 + 4];
        vv[0] += r0v.x; vv[1] += r0v.y; vv[2] += r0v.z; vv[3] += r0v.w;
        vv[4] += r1v.x; vv[5] += r1v.y; vv[6] += r1v.z; vv[7] += r1v.w;
    }
    if (act) {
#pragma unroll
        for (int i = 0; i < 8; ++i)
            vv[i] = vv[i] > 0.f ? vv[i] : __expf(vv[i]) - 1.f;
    }
    if (MEAN_HEADS) {
        float ov[8];
#pragma unroll
        for (int i = 0; i < 8; ++i) ov[i] = __shfl_xor(vv[i], CH / 2);
        if (es == 0 && c < CH / 2) {
            float4 u0 = make_float4(0.5f * (vv[0] + ov[0]), 0.5f * (vv[1] + ov[1]),
                                    0.5f * (vv[2] + ov[2]), 0.5f * (vv[3] + ov[3]));
            float4 u1 = make_float4(0.5f * (vv[4] + ov[4]), 0.5f * (vv[5] + ov[5]),
                                    0.5f * (vv[6] + ov[6]), 0.5f * (vv[7] + ov[7]));
            *(float4*)&out[(size_t)node * D + f0] = u0;
            *(float4*)&out[(size_t)node * D + f0 + 4] = u1;
        }
    } else {
        if (es == 0) {
            *(float4*)&out[(size_t)node * F + f0] =
                make_float4(vv[0], vv[1], vv[2], vv[3]);
            *(float4*)&out[(size_t)node * F + f0 + 4] =
                make_float4(vv[4], vv[5], vv[6], vv[7]);
        }
    }
}

// ---------------------------------------------------------------------------

extern "C" void kernel_launch(void* const* d_in, const int* in_sizes, int n_in,
                              void* d_out, int out_size, void* d_ws, size_t ws_size,
                              hipStream_t stream) {
    const float* x     = (const float*)d_in[0];
    const int*   esrc  = (const int*)d_in[1];
    const int*   edst  = (const int*)d_in[2];
    const float* W0    = (const float*)d_in[3];
    const float* al0   = (const float*)d_in[4];
    const float* ar0   = (const float*)d_in[5];
    const float* b0    = (const float*)d_in[6];
    const float* W1    = (const float*)d_in[7];
    const float* al1   = (const float*)d_in[8];
    const float* ar1   = (const float*)d_in[9];
    const float* b1    = (const float*)d_in[10];
    const float* W2    = (const float*)d_in[11];
    const float* al2   = (const float*)d_in[12];
    const float* ar2   = (const float*)d_in[13];
    const float* b2    = (const float*)d_in[14];
    const float* Wres2 = (const float*)d_in[15];

    const int N = in_sizes[0] / 256;  // 50000
    const int E = in_sizes[1];        // 800000

    // workspace layout
    float* ws = (float*)d_ws;
    float* A    = ws;                       // [N,128] agg0 out / L1 gemm in
    float* B    = A + (size_t)N * 128;      // [N,128] agg1 out / L2 gemm in
    float* hres = B + (size_t)N * 128;      // [N,64]  L2 projected residual
    float* el   = hres + (size_t)N * 64;    // [N,2]
    float* er   = el + (size_t)N * 2;       // [N,2]
    int* deg    = (int*)(er + (size_t)N * 2);
    int* offs   = deg + N;
    int* cursor = offs + N;
    int* incl   = cursor + N;
    int* bsums  = incl + N;                 // 256 ints
    int* ssrc   = bsums + 256;              // [E]
    ushort* Hb  = (ushort*)(ssrc + E);      // [N,128] bf16 h for gathers

    // ---- CSR-by-destination build ----
    hipMemsetAsync(deg, 0, (size_t)N * sizeof(int), stream);
    hipMemsetAsync(cursor, 0, (size_t)N * sizeof(int), stream);
    hist_k<<<(E + 255) / 256, 256, 0, stream>>>(edst, E, deg);
    int nb = (N + 511) / 512;  // 98 <= 128
    scan1_k<<<nb, 512, 0, stream>>>(deg, N, incl, bsums);
    scan2_k<<<1, 128, 0, stream>>>(bsums, nb);
    scan3_k<<<(N + 255) / 256, 256, 0, stream>>>(incl, deg, bsums, offs, N);
    scatter_k<<<(E + 255) / 256, 256, 0, stream>>>(esrc, edst, E, offs, cursor, ssrc);

    int gblk = 2 * ((N + 63) / 64);  // 1564: rowTiles x 2 col-tiles
    int ablk = (N + 3) / 4;          // wave per node

    // ---- Layer 0: IN=256 -> [N,2,64], ELU ----
    gemm_s<256, false><<<gblk, 256, 0, stream>>>(x, W0, nullptr, nullptr, Hb, N,
                                                 al0, ar0, el, er);
    agg_b<64, false><<<ablk, 256, 0, stream>>>(ssrc, offs, deg, Hb, el, er, b0,
                                               nullptr, A, 1, N);

    // ---- Layer 1: 128 -> [N,2,64], identity residual, ELU ----
    gemm_s<128, false><<<gblk, 256, 0, stream>>>(A, W1, nullptr, nullptr, Hb, N,
                                                 al1, ar1, el, er);
    agg_b<64, false><<<ablk, 256, 0, stream>>>(ssrc, offs, deg, Hb, el, er, b1,
                                               A, B, 1, N);

    // ---- Layer 2: 128 -> [N,2,32], W2 + Wres2 fused (two col-tiles) ----
    gemm_s<128, true><<<gblk, 256, 0, stream>>>(B, W2, Wres2, hres, Hb, N,
                                                al2, ar2, el, er);
    agg_b<32, true><<<ablk, 256, 0, stream>>>(ssrc, offs, deg, Hb, el, er, b2,
                                              hres, (float*)d_out, 0, N);
}

// Round 8
// 365.960 us; speedup vs baseline: 3.2722x; 1.2090x over previous
//
#include <hip/hip_runtime.h>
#include <math.h>

// ---------------------------------------------------------------------------
// GAT, 3 layers, N=50000, E=800000, H=2 heads, D=64/64/32.
// CSR-by-dst per launch; bf16 MFMA GEMM (16x16x32, 64x128 block tile) with
// fused el/er + bf16-h epilogue; wave-per-node bf16 aggregate.
// ---------------------------------------------------------------------------

typedef unsigned int uint;
typedef unsigned short ushort;
typedef __attribute__((ext_vector_type(8))) short bf16x8;
typedef __attribute__((ext_vector_type(4))) float f32x4;

__device__ inline uint f2bf(float f) {  // fp32 -> bf16 bits, RNE
    uint u = __float_as_uint(f);
    return (u + 0x7fffu + ((u >> 16) & 1u)) >> 16;
}

__device__ inline uint4 pack8(float4 a, float4 b) {
    return make_uint4(f2bf(a.x) | (f2bf(a.y) << 16), f2bf(a.z) | (f2bf(a.w) << 16),
                      f2bf(b.x) | (f2bf(b.y) << 16), f2bf(b.z) | (f2bf(b.w) << 16));
}

__global__ __launch_bounds__(256) void hist_k(const int* __restrict__ dst, int E,
                                              int* __restrict__ deg) {
    int e = blockIdx.x * 256 + threadIdx.x;
    if (e < E) atomicAdd(&deg[dst[e]], 1);
}

__global__ __launch_bounds__(512) void scan1_k(const int* __restrict__ deg, int n,
                                               int* __restrict__ incl,
                                               int* __restrict__ bsums) {
    __shared__ int sm[512];
    int t = threadIdx.x;
    int i = blockIdx.x * 512 + t;
    int v = (i < n) ? deg[i] : 0;
    sm[t] = v;
    __syncthreads();
    for (int ofs = 1; ofs < 512; ofs <<= 1) {
        int add = (t >= ofs) ? sm[t - ofs] : 0;
        __syncthreads();
        sm[t] += add;
        __syncthreads();
    }
    if (i < n) incl[i] = sm[t];
    if (t == 511) bsums[blockIdx.x] = sm[511];
}

__global__ __launch_bounds__(128) void scan2_k(int* __restrict__ bsums, int nb) {
    __shared__ int sm[128];
    int t = threadIdx.x;
    int v = (t < nb) ? bsums[t] : 0;
    sm[t] = v;
    __syncthreads();
    for (int ofs = 1; ofs < 128; ofs <<= 1) {
        int add = (t >= ofs) ? sm[t - ofs] : 0;
        __syncthreads();
        sm[t] += add;
        __syncthreads();
    }
    if (t < nb) bsums[t] = sm[t] - v;  // exclusive
}

__global__ __launch_bounds__(256) void scan3_k(const int* __restrict__ incl,
                                               const int* __restrict__ deg,
                                               const int* __restrict__ bsumsx,
                                               int* __restrict__ offs, int n) {
    int i = blockIdx.x * 256 + threadIdx.x;
    if (i < n) offs[i] = bsumsx[i >> 9] + incl[i] - deg[i];
}

__global__ __launch_bounds__(256) void scatter_k(const int* __restrict__ src,
                                                 const int* __restrict__ dst, int E,
                                                 const int* __restrict__ offs,
                                                 int* __restrict__ cursor,
                                                 int* __restrict__ ssrc) {
    int e = blockIdx.x * 256 + threadIdx.x;
    if (e < E) {
        int d = dst[e];
        int pos = offs[d] + atomicAdd(&cursor[d], 1);
        ssrc[pos] = src[e];
    }
}

// ---------------------------------------------------------------------------
// Weight prep (once per launch): Wt[n][k] = bf16(W[k][n]).
// W0 256x128 -> Wt0[128][256]; W1 128x128 -> Wt1[128][128];
// W2 128x64 -> Wt2cat[0..63][128]; Wres2 128x64 -> Wt2cat[64..127][128].
// ---------------------------------------------------------------------------
__global__ __launch_bounds__(256) void wt_k(
    const float* __restrict__ W0, const float* __restrict__ W1,
    const float* __restrict__ W2, const float* __restrict__ Wr,
    ushort* __restrict__ Wt0, ushort* __restrict__ Wt1,
    ushort* __restrict__ Wt2cat) {
    int b = blockIdx.x, t = threadIdx.x;
    if (b < 128) {           // W0: 32768 elems
        int i = b * 256 + t;
        int n = i >> 8, k = i & 255;
        Wt0[n * 256 + k] = (ushort)f2bf(W0[k * 128 + n]);
    } else if (b < 192) {    // W1: 16384
        int i = (b - 128) * 256 + t;
        int n = i >> 7, k = i & 127;
        Wt1[n * 128 + k] = (ushort)f2bf(W1[k * 128 + n]);
    } else if (b < 224) {    // W2: 8192
        int i = (b - 192) * 256 + t;
        int n = i >> 7, k = i & 127;
        Wt2cat[n * 128 + k] = (ushort)f2bf(W2[k * 64 + n]);
    } else {                 // Wres2: 8192
        int i = (b - 224) * 256 + t;
        int n = i >> 7, k = i & 127;
        Wt2cat[(64 + n) * 128 + k] = (ushort)f2bf(Wr[k * 64 + n]);
    }
}

// ---------------------------------------------------------------------------
// MFMA GEMM: C[64 rows x 128 cols] = A[rows,K] * Wt^T.  BK=64, 4 waves, each
// wave owns 16 rows x 128 cols (8 mfma tiles).  A staged fp32->bf16 (AFP32)
// or bf16 passthrough; Wt rows are K-contiguous (pre-transposed).
// Epilogue via LDS: bf16 Hb, fp32 hres (L2MODE cols 64-127), fused el/er.
// Fragments (verified layouts): A[m=lane&15][k=quad*8+j]; B from Bt[n][k]
// rows; C/D col=lane&15, row=quad*4+reg.
// ---------------------------------------------------------------------------
template <int K, bool L2MODE, bool AFP32>
__global__ __launch_bounds__(256) void gemm_m(
    const float* __restrict__ Af, const ushort* __restrict__ Ab,
    const ushort* __restrict__ Wt, ushort* __restrict__ Hb,
    float* __restrict__ hres, int nrows,
    const float* __restrict__ al, const float* __restrict__ ar,
    float* __restrict__ el, float* __restrict__ er) {
    constexpr int BK = 64;
    constexpr int AS = 72;            // LDS row stride in bf16 (144B, 16B-mult)
    __shared__ float smem[8448 + 256];
    ushort* As = (ushort*)smem;               // 64 x 72 bf16
    ushort* Ws = (ushort*)smem + 64 * AS;     // 128 x 72 bf16
    float* alr = smem + 8448;                 // staged al|ar
    const int tid = threadIdx.x;
    const int w = tid >> 6;
    const int lane = tid & 63;
    const int l15 = lane & 15, quad = lane >> 4;
    const int row0 = blockIdx.x * 64;
    constexpr int NC = L2MODE ? 64 : 128;

    if (tid < 2 * NC) alr[tid] = (tid < NC) ? al[tid] : ar[tid - NC];

    f32x4 acc[8];
#pragma unroll
    for (int i = 0; i < 8; ++i) acc[i] = (f32x4){0.f, 0.f, 0.f, 0.f};

    for (int kt = 0; kt < K / BK; ++kt) {
        const int k0 = kt * BK;
        if (AFP32) {
            // 64 rows x 16 chunks of 4k: load float4, cvt, 8B ds write
#pragma unroll
            for (int t = 0; t < 4; ++t) {
                int idx = tid + t * 256;
                int r = idx >> 4, c4 = idx & 15;
                float4 v = make_float4(0.f, 0.f, 0.f, 0.f);
                if (row0 + r < nrows)
                    v = *(const float4*)&Af[(size_t)(row0 + r) * K + k0 + c4 * 4];
                ushort4 o;
                o.x = (ushort)f2bf(v.x); o.y = (ushort)f2bf(v.y);
                o.z = (ushort)f2bf(v.z); o.w = (ushort)f2bf(v.w);
                *(ushort4*)&As[r * AS + c4 * 4] = o;
            }
        } else {
            // 64 rows x 8 chunks of 8k: 16B copy
#pragma unroll
            for (int t = 0; t < 2; ++t) {
                int idx = tid + t * 256;
                int r = idx >> 3, c8 = idx & 7;
                uint4 v = make_uint4(0, 0, 0, 0);
                if (row0 + r < nrows)
                    v = *(const uint4*)&Ab[(size_t)(row0 + r) * K + k0 + c8 * 8];
                *(uint4*)&As[r * AS + c8 * 8] = v;
            }
        }
        // Wt tile: 128 n x 8 chunks of 8k
#pragma unroll
        for (int t = 0; t < 4; ++t) {
            int idx = tid + t * 256;
            int n = idx >> 3, c8 = idx & 7;
            *(uint4*)&Ws[n * AS + c8 * 8] =
                *(const uint4*)&Wt[(size_t)n * K + k0 + c8 * 8];
        }
        __syncthreads();
#pragma unroll
        for (int ks = 0; ks < 2; ++ks) {
            bf16x8 af = *(const bf16x8*)&As[(w * 16 + l15) * AS + ks * 32 + quad * 8];
#pragma unroll
            for (int ct = 0; ct < 8; ++ct) {
                bf16x8 bf = *(const bf16x8*)&Ws[(ct * 16 + l15) * AS + ks * 32 + quad * 8];
                acc[ct] = __builtin_amdgcn_mfma_f32_16x16x32_bf16(af, bf, acc[ct], 0, 0, 0);
            }
        }
        __syncthreads();
    }

    // ---- epilogue: C tile -> LDS (64 x 132 fp32) ----
    float* Cs = smem;
#pragma unroll
    for (int ct = 0; ct < 8; ++ct)
#pragma unroll
        for (int r = 0; r < 4; ++r)
            Cs[(w * 16 + quad * 4 + r) * 132 + ct * 16 + l15] = acc[ct][r];
    __syncthreads();

    if (L2MODE) {
        // Hb: cols 0-63 bf16 (row stride 64)
#pragma unroll
        for (int t = 0; t < 2; ++t) {
            int chunk = tid + t * 256;
            int r = chunk >> 3, c8 = chunk & 7;
            int grow = row0 + r;
            if (grow < nrows) {
                float4 v0 = *(float4*)&Cs[r * 132 + c8 * 8];
                float4 v1 = *(float4*)&Cs[r * 132 + c8 * 8 + 4];
                *(uint4*)&Hb[(size_t)grow * 64 + c8 * 8] = pack8(v0, v1);
            }
        }
        // hres: cols 64-127 fp32
#pragma unroll
        for (int t = 0; t < 4; ++t) {
            int chunk = tid + t * 256;
            int r = chunk >> 4, c4 = chunk & 15;
            int grow = row0 + r;
            if (grow < nrows)
                *(float4*)&hres[(size_t)grow * 64 + c4 * 4] =
                    *(float4*)&Cs[r * 132 + 64 + c4 * 4];
        }
    } else {
        // Hb: 128 cols bf16
#pragma unroll
        for (int t = 0; t < 4; ++t) {
            int chunk = tid + t * 256;
            int r = chunk >> 4, c8 = chunk & 15;
            int grow = row0 + r;
            if (grow < nrows) {
                float4 v0 = *(float4*)&Cs[r * 132 + c8 * 8];
                float4 v1 = *(float4*)&Cs[r * 132 + c8 * 8 + 4];
                *(uint4*)&Hb[(size_t)grow * 128 + c8 * 8] = pack8(v0, v1);
            }
        }
    }
    // el/er: 64 rows x 2 heads x {el,er} = 256 threads
    {
        constexpr int HD = L2MODE ? 32 : 64;
        int r = tid >> 2, hh = (tid >> 1) & 1, iser = tid & 1;
        int grow = row0 + r;
        const float* coef = alr + iser * NC + hh * HD;
        const float* crow = Cs + r * 132 + hh * HD;
        float sum = 0.f;
#pragma unroll
        for (int i = 0; i < HD; ++i) sum += crow[i] * coef[i];
        if (grow < nrows) (iser ? er : el)[grow * 2 + hh] = sum;
    }
}

// ---------------------------------------------------------------------------
// Aggregation, bf16 gather: one wave per node (both heads).  Row = 2*D bf16
// = CH uint4 chunks; ES = 64/CH edges per wave iteration (1KB/load).
// Softmax fast path (deg<=64); shuffle-broadcast weights; fp32 accumulate;
// fused bias/residual/ELU/head-mean epilogue; optional fp32 + bf16 outputs.
// ---------------------------------------------------------------------------
template <int D, bool MEAN_HEADS>
__global__ __launch_bounds__(256) void agg_b(
    const int* __restrict__ ssrc, const int* __restrict__ offs,
    const int* __restrict__ deg, const ushort* __restrict__ hb,
    const float* __restrict__ el, const float* __restrict__ er,
    const float* __restrict__ bias, const float* __restrict__ res,
    float* __restrict__ out, ushort* __restrict__ outb, int act, int n) {
    constexpr int F = 2 * D;
    constexpr int CH = F / 8;
    constexpr int ES = 64 / CH;
    const int wid = threadIdx.x >> 6;
    const int lane = threadIdx.x & 63;
    const int node = blockIdx.x * 4 + wid;
    if (node >= n) return;
    const int off = offs[node];
    const int dg = deg[node];
    const float2 ern = *(const float2*)&er[node * 2];

    float m0, m1, is0, is1;
    float w0r = 0.f, w1r = 0.f;
    int sidx_r = 0;
    const bool small = (dg <= 64);
    if (small) {
        float a = -INFINITY, b = -INFINITY;
        if (lane < dg) {
            sidx_r = ssrc[off + lane];
            float2 ev = *(const float2*)&el[sidx_r * 2];
            a = ev.x + ern.x; a = a >= 0.f ? a : 0.2f * a;
            b = ev.y + ern.y; b = b >= 0.f ? b : 0.2f * b;
        }
        m0 = a; m1 = b;
        for (int o = 32; o; o >>= 1) {
            m0 = fmaxf(m0, __shfl_xor(m0, o));
            m1 = fmaxf(m1, __shfl_xor(m1, o));
        }
        float p0 = (lane < dg) ? __expf(a - m0) : 0.f;
        float p1 = (lane < dg) ? __expf(b - m1) : 0.f;
        float s0 = p0, s1 = p1;
        for (int o = 32; o; o >>= 1) {
            s0 += __shfl_xor(s0, o);
            s1 += __shfl_xor(s1, o);
        }
        is0 = s0 > 0.f ? 1.f / s0 : 0.f;
        is1 = s1 > 0.f ? 1.f / s1 : 0.f;
        w0r = p0 * is0;
        w1r = p1 * is1;
    } else {
        float s0 = 0.f, s1 = 0.f;
        m0 = -INFINITY; m1 = -INFINITY;
        for (int k = lane; k < dg; k += 64) {
            int sidx = ssrc[off + k];
            float2 ev = *(const float2*)&el[sidx * 2];
            float a = ev.x + ern.x; a = a >= 0.f ? a : 0.2f * a;
            float b = ev.y + ern.y; b = b >= 0.f ? b : 0.2f * b;
            float nm = fmaxf(m0, a);
            s0 = s0 * __expf(m0 - nm) + __expf(a - nm); m0 = nm;
            nm = fmaxf(m1, b);
            s1 = s1 * __expf(m1 - nm) + __expf(b - nm); m1 = nm;
        }
        for (int o = 32; o; o >>= 1) {
            float om = __shfl_xor(m0, o), os = __shfl_xor(s0, o);
            float nm = fmaxf(m0, om);
            s0 = (nm == -INFINITY) ? 0.f : s0 * __expf(m0 - nm) + os * __expf(om - nm);
            m0 = nm;
            om = __shfl_xor(m1, o); os = __shfl_xor(s1, o);
            nm = fmaxf(m1, om);
            s1 = (nm == -INFINITY) ? 0.f : s1 * __expf(m1 - nm) + os * __expf(om - nm);
            m1 = nm;
        }
        is0 = s0 > 0.f ? 1.f / s0 : 0.f;
        is1 = s1 > 0.f ? 1.f / s1 : 0.f;
    }

    const int c = lane & (CH - 1);
    const int es = lane / CH;
    const bool head1 = (c >= CH / 2);
    const uint4* __restrict__ hp = (const uint4*)hb;
    float acc[8];
#pragma unroll
    for (int i = 0; i < 8; ++i) acc[i] = 0.f;

    for (int c0 = 0; c0 < dg; c0 += 64) {
        float w0, w1;
        int sidx;
        if (small) {
            sidx = sidx_r; w0 = w0r; w1 = w1r;
        } else {
            int k = c0 + lane;
            if (k < dg) {
                sidx = ssrc[off + k];
                float2 ev = *(const float2*)&el[sidx * 2];
                float a = ev.x + ern.x; a = a >= 0.f ? a : 0.2f * a;
                float b = ev.y + ern.y; b = b >= 0.f ? b : 0.2f * b;
                w0 = __expf(a - m0) * is0;
                w1 = __expf(b - m1) * is1;
            } else {
                sidx = 0; w0 = 0.f; w1 = 0.f;
            }
        }
        const int cnt = min(64, dg - c0);
        for (int p = 0; p < cnt; p += ES) {
            int j = p + es;
            int jc = (j < cnt) ? j : 0;
            int sj = __shfl(sidx, jc);
            float wa = __shfl(w0, jc);
            float wb = __shfl(w1, jc);
            float wj = (j < cnt) ? (head1 ? wb : wa) : 0.f;
            uint4 q = hp[(size_t)sj * CH + c];
            acc[0] += wj * __uint_as_float(q.x << 16);
            acc[1] += wj * __uint_as_float(q.x & 0xffff0000u);
            acc[2] += wj * __uint_as_float(q.y << 16);
            acc[3] += wj * __uint_as_float(q.y & 0xffff0000u);
            acc[4] += wj * __uint_as_float(q.z << 16);
            acc[5] += wj * __uint_as_float(q.z & 0xffff0000u);
            acc[6] += wj * __uint_as_float(q.w << 16);
            acc[7] += wj * __uint_as_float(q.w & 0xffff0000u);
        }
    }

#pragma unroll
    for (int o = CH; o < 64; o <<= 1) {
#pragma unroll
        for (int i = 0; i < 8; ++i) acc[i] += __shfl_xor(acc[i], o);
    }

    const int f0 = c * 8;
    float4 b0v = *(const float4*)&bias[f0];
    float4 b1v = *(const float4*)&bias[f0 + 4];
    float vv[8] = {acc[0] + b0v.x, acc[1] + b0v.y, acc[2] + b0v.z, acc[3] + b0v.w,
                   acc[4] + b1v.x, acc[5] + b1v.y, acc[6] + b1v.z, acc[7] + b1v.w};
    if (res) {
        float4 r0v = *(const float4*)&res[(size_t)node * F + f0];
        float4 r1v = *(const float4*)&res[(size_t)node * F + f0 + 4];
        vv[0] += r0v.x; vv[1] += r0v.y; vv[2] += r0v.z; vv[3] += r0v.w;
        vv[4] += r1v.x; vv[5] += r1v.y; vv[6] += r1v.z; vv[7] += r1v.w;
    }
    if (act) {
#pragma unroll
        for (int i = 0; i < 8; ++i)
            vv[i] = vv[i] > 0.f ? vv[i] : __expf(vv[i]) - 1.f;
    }
    if (MEAN_HEADS) {
        float ov[8];
#pragma unroll
        for (int i = 0; i < 8; ++i) ov[i] = __shfl_xor(vv[i], CH / 2);
        if (es == 0 && c < CH / 2) {
            float4 u0 = make_float4(0.5f * (vv[0] + ov[0]), 0.5f * (vv[1] + ov[1]),
                                    0.5f * (vv[2] + ov[2]), 0.5f * (vv[3] + ov[3]));
            float4 u1 = make_float4(0.5f * (vv[4] + ov[4]), 0.5f * (vv[5] + ov[5]),
                                    0.5f * (vv[6] + ov[6]), 0.5f * (vv[7] + ov[7]));
            *(float4*)&out[(size_t)node * D + f0] = u0;
            *(float4*)&out[(size_t)node * D + f0 + 4] = u1;
        }
    } else if (es == 0) {
        if (out) {
            *(float4*)&out[(size_t)node * F + f0] =
                make_float4(vv[0], vv[1], vv[2], vv[3]);
            *(float4*)&out[(size_t)node * F + f0 + 4] =
                make_float4(vv[4], vv[5], vv[6], vv[7]);
        }
        if (outb) {
            *(uint4*)&outb[(size_t)node * F + f0] =
                pack8(make_float4(vv[0], vv[1], vv[2], vv[3]),
                      make_float4(vv[4], vv[5], vv[6], vv[7]));
        }
    }
}

// ---------------------------------------------------------------------------

extern "C" void kernel_launch(void* const* d_in, const int* in_sizes, int n_in,
                              void* d_out, int out_size, void* d_ws, size_t ws_size,
                              hipStream_t stream) {
    const float* x     = (const float*)d_in[0];
    const int*   esrc  = (const int*)d_in[1];
    const int*   edst  = (const int*)d_in[2];
    const float* W0    = (const float*)d_in[3];
    const float* al0   = (const float*)d_in[4];
    const float* ar0   = (const float*)d_in[5];
    const float* b0    = (const float*)d_in[6];
    const float* W1    = (const float*)d_in[7];
    const float* al1   = (const float*)d_in[8];
    const float* ar1   = (const float*)d_in[9];
    const float* b1    = (const float*)d_in[10];
    const float* W2    = (const float*)d_in[11];
    const float* al2   = (const float*)d_in[12];
    const float* ar2   = (const float*)d_in[13];
    const float* b2    = (const float*)d_in[14];
    const float* Wres2 = (const float*)d_in[15];

    const int N = in_sizes[0] / 256;  // 50000
    const int E = in_sizes[1];        // 800000

    // workspace layout
    float* ws = (float*)d_ws;
    float* A     = ws;                      // [N,128] fp32 agg0 out (L1 residual)
    float* hres  = A + (size_t)N * 128;     // [N,64]  L2 projected residual
    float* el    = hres + (size_t)N * 64;   // [N,2]
    float* er    = el + (size_t)N * 2;      // [N,2]
    int* deg     = (int*)(er + (size_t)N * 2);
    int* offs    = deg + N;
    int* cursor  = offs + N;
    int* incl    = cursor + N;
    int* bsums   = incl + N;                // 256 ints
    int* ssrc    = bsums + 256;             // [E]
    ushort* Hb   = (ushort*)(ssrc + E);     // [N,128] bf16 gemm out (gather src)
    ushort* Ab   = Hb + (size_t)N * 128;    // [N,128] bf16 agg0 out (L1 gemm in)
    ushort* Bb   = Ab + (size_t)N * 128;    // [N,128] bf16 agg1 out (L2 gemm in)
    ushort* Wt0  = Bb + (size_t)N * 128;    // [128,256] bf16 W0^T
    ushort* Wt1  = Wt0 + 128 * 256;         // [128,128] bf16 W1^T
    ushort* Wt2c = Wt1 + 128 * 128;         // [128,128] bf16 [W2|Wres2]^T

    // ---- CSR-by-destination build ----
    hipMemsetAsync(deg, 0, (size_t)N * sizeof(int), stream);
    hipMemsetAsync(cursor, 0, (size_t)N * sizeof(int), stream);
    hist_k<<<(E + 255) / 256, 256, 0, stream>>>(edst, E, deg);
    int nb = (N + 511) / 512;  // 98 <= 128
    scan1_k<<<nb, 512, 0, stream>>>(deg, N, incl, bsums);
    scan2_k<<<1, 128, 0, stream>>>(bsums, nb);
    scan3_k<<<(N + 255) / 256, 256, 0, stream>>>(incl, deg, bsums, offs, N);
    scatter_k<<<(E + 255) / 256, 256, 0, stream>>>(esrc, edst, E, offs, cursor, ssrc);

    // ---- weight prep ----
    wt_k<<<256, 256, 0, stream>>>(W0, W1, W2, Wres2, Wt0, Wt1, Wt2c);

    int gblk = (N + 63) / 64;  // 782
    int ablk = (N + 3) / 4;    // wave per node

    // ---- Layer 0: IN=256 -> [N,2,64], ELU ----
    gemm_m<256, false, true><<<gblk, 256, 0, stream>>>(
        x, nullptr, Wt0, Hb, nullptr, N, al0, ar0, el, er);
    agg_b<64, false><<<ablk, 256, 0, stream>>>(ssrc, offs, deg, Hb, el, er, b0,
                                               nullptr, A, Ab, 1, N);

    // ---- Layer 1: 128 -> [N,2,64], identity residual (A), ELU ----
    gemm_m<128, false, false><<<gblk, 256, 0, stream>>>(
        nullptr, Ab, Wt1, Hb, nullptr, N, al1, ar1, el, er);
    agg_b<64, false><<<ablk, 256, 0, stream>>>(ssrc, offs, deg, Hb, el, er, b1,
                                               A, nullptr, Bb, 1, N);

    // ---- Layer 2: 128 -> [N,2,32], W2+Wres2 fused, head-mean ----
    gemm_m<128, true, false><<<gblk, 256, 0, stream>>>(
        nullptr, Bb, Wt2c, Hb, hres, N, al2, ar2, el, er);
    agg_b<32, true><<<ablk, 256, 0, stream>>>(ssrc, offs, deg, Hb, el, er, b2,
                                              hres, (float*)d_out, nullptr, 0, N);
}

// Round 9
// 365.079 us; speedup vs baseline: 3.2801x; 1.0024x over previous
//
#include <hip/hip_runtime.h>
#include <math.h>

// ---------------------------------------------------------------------------
// GAT, 3 layers, N=50000, E=800000, H=2 heads, D=64/64/32.
// CSR-by-dst per launch; bf16 MFMA GEMM (16x16x32, 64x128 block tile) with
// fused el/er + bf16-h epilogue; wave-per-node bf16 aggregate with 4-deep
// batched gather loads (MLP for latency hiding).
// ---------------------------------------------------------------------------

typedef unsigned int uint;
typedef unsigned short ushort;
typedef __attribute__((ext_vector_type(8))) short bf16x8;
typedef __attribute__((ext_vector_type(4))) float f32x4;

__device__ inline uint f2bf(float f) {  // fp32 -> bf16 bits, RNE
    uint u = __float_as_uint(f);
    return (u + 0x7fffu + ((u >> 16) & 1u)) >> 16;
}

__device__ inline uint4 pack8(float4 a, float4 b) {
    return make_uint4(f2bf(a.x) | (f2bf(a.y) << 16), f2bf(a.z) | (f2bf(a.w) << 16),
                      f2bf(b.x) | (f2bf(b.y) << 16), f2bf(b.z) | (f2bf(b.w) << 16));
}

__global__ __launch_bounds__(256) void hist_k(const int* __restrict__ dst, int E,
                                              int* __restrict__ deg) {
    int e = blockIdx.x * 256 + threadIdx.x;
    if (e < E) atomicAdd(&deg[dst[e]], 1);
}

__global__ __launch_bounds__(512) void scan1_k(const int* __restrict__ deg, int n,
                                               int* __restrict__ incl,
                                               int* __restrict__ bsums) {
    __shared__ int sm[512];
    int t = threadIdx.x;
    int i = blockIdx.x * 512 + t;
    int v = (i < n) ? deg[i] : 0;
    sm[t] = v;
    __syncthreads();
    for (int ofs = 1; ofs < 512; ofs <<= 1) {
        int add = (t >= ofs) ? sm[t - ofs] : 0;
        __syncthreads();
        sm[t] += add;
        __syncthreads();
    }
    if (i < n) incl[i] = sm[t];
    if (t == 511) bsums[blockIdx.x] = sm[511];
}

__global__ __launch_bounds__(128) void scan2_k(int* __restrict__ bsums, int nb) {
    __shared__ int sm[128];
    int t = threadIdx.x;
    int v = (t < nb) ? bsums[t] : 0;
    sm[t] = v;
    __syncthreads();
    for (int ofs = 1; ofs < 128; ofs <<= 1) {
        int add = (t >= ofs) ? sm[t - ofs] : 0;
        __syncthreads();
        sm[t] += add;
        __syncthreads();
    }
    if (t < nb) bsums[t] = sm[t] - v;  // exclusive
}

__global__ __launch_bounds__(256) void scan3_k(const int* __restrict__ incl,
                                               const int* __restrict__ deg,
                                               const int* __restrict__ bsumsx,
                                               int* __restrict__ offs, int n) {
    int i = blockIdx.x * 256 + threadIdx.x;
    if (i < n) offs[i] = bsumsx[i >> 9] + incl[i] - deg[i];
}

__global__ __launch_bounds__(256) void scatter_k(const int* __restrict__ src,
                                                 const int* __restrict__ dst, int E,
                                                 const int* __restrict__ offs,
                                                 int* __restrict__ cursor,
                                                 int* __restrict__ ssrc) {
    int e = blockIdx.x * 256 + threadIdx.x;
    if (e < E) {
        int d = dst[e];
        int pos = offs[d] + atomicAdd(&cursor[d], 1);
        ssrc[pos] = src[e];
    }
}

// ---------------------------------------------------------------------------
// Weight prep (once per launch): Wt[n][k] = bf16(W[k][n]).
// ---------------------------------------------------------------------------
__global__ __launch_bounds__(256) void wt_k(
    const float* __restrict__ W0, const float* __restrict__ W1,
    const float* __restrict__ W2, const float* __restrict__ Wr,
    ushort* __restrict__ Wt0, ushort* __restrict__ Wt1,
    ushort* __restrict__ Wt2cat) {
    int b = blockIdx.x, t = threadIdx.x;
    if (b < 128) {           // W0: 32768 elems
        int i = b * 256 + t;
        int n = i >> 8, k = i & 255;
        Wt0[n * 256 + k] = (ushort)f2bf(W0[k * 128 + n]);
    } else if (b < 192) {    // W1: 16384
        int i = (b - 128) * 256 + t;
        int n = i >> 7, k = i & 127;
        Wt1[n * 128 + k] = (ushort)f2bf(W1[k * 128 + n]);
    } else if (b < 224) {    // W2: 8192
        int i = (b - 192) * 256 + t;
        int n = i >> 7, k = i & 127;
        Wt2cat[n * 128 + k] = (ushort)f2bf(W2[k * 64 + n]);
    } else {                 // Wres2: 8192
        int i = (b - 224) * 256 + t;
        int n = i >> 7, k = i & 127;
        Wt2cat[(64 + n) * 128 + k] = (ushort)f2bf(Wr[k * 64 + n]);
    }
}

// ---------------------------------------------------------------------------
// MFMA GEMM: C[64 rows x 128 cols] = A[rows,K] * Wt^T.  BK=64, 4 waves, each
// wave owns 16 rows x 128 cols (8 mfma tiles).  Verified fragment layouts:
// A[m=lane&15][k=quad*8+j]; B from Bt[n][k] rows; C/D col=lane&15,
// row=quad*4+reg.  Epilogue via LDS: bf16 Hb, fp32 hres, fused el/er.
// ---------------------------------------------------------------------------
template <int K, bool L2MODE, bool AFP32>
__global__ __launch_bounds__(256) void gemm_m(
    const float* __restrict__ Af, const ushort* __restrict__ Ab,
    const ushort* __restrict__ Wt, ushort* __restrict__ Hb,
    float* __restrict__ hres, int nrows,
    const float* __restrict__ al, const float* __restrict__ ar,
    float* __restrict__ el, float* __restrict__ er) {
    constexpr int BK = 64;
    constexpr int AS = 72;            // LDS row stride in bf16
    __shared__ float smem[8448 + 256];
    ushort* As = (ushort*)smem;               // 64 x 72 bf16
    ushort* Ws = (ushort*)smem + 64 * AS;     // 128 x 72 bf16
    float* alr = smem + 8448;                 // staged al|ar
    const int tid = threadIdx.x;
    const int w = tid >> 6;
    const int lane = tid & 63;
    const int l15 = lane & 15, quad = lane >> 4;
    const int row0 = blockIdx.x * 64;
    constexpr int NC = L2MODE ? 64 : 128;

    if (tid < 2 * NC) alr[tid] = (tid < NC) ? al[tid] : ar[tid - NC];

    f32x4 acc[8];
#pragma unroll
    for (int i = 0; i < 8; ++i) acc[i] = (f32x4){0.f, 0.f, 0.f, 0.f};

    for (int kt = 0; kt < K / BK; ++kt) {
        const int k0 = kt * BK;
        if (AFP32) {
#pragma unroll
            for (int t = 0; t < 4; ++t) {
                int idx = tid + t * 256;
                int r = idx >> 4, c4 = idx & 15;
                float4 v = make_float4(0.f, 0.f, 0.f, 0.f);
                if (row0 + r < nrows)
                    v = *(const float4*)&Af[(size_t)(row0 + r) * K + k0 + c4 * 4];
                ushort4 o;
                o.x = (ushort)f2bf(v.x); o.y = (ushort)f2bf(v.y);
                o.z = (ushort)f2bf(v.z); o.w = (ushort)f2bf(v.w);
                *(ushort4*)&As[r * AS + c4 * 4] = o;
            }
        } else {
#pragma unroll
            for (int t = 0; t < 2; ++t) {
                int idx = tid + t * 256;
                int r = idx >> 3, c8 = idx & 7;
                uint4 v = make_uint4(0, 0, 0, 0);
                if (row0 + r < nrows)
                    v = *(const uint4*)&Ab[(size_t)(row0 + r) * K + k0 + c8 * 8];
                *(uint4*)&As[r * AS + c8 * 8] = v;
            }
        }
#pragma unroll
        for (int t = 0; t < 4; ++t) {
            int idx = tid + t * 256;
            int n = idx >> 3, c8 = idx & 7;
            *(uint4*)&Ws[n * AS + c8 * 8] =
                *(const uint4*)&Wt[(size_t)n * K + k0 + c8 * 8];
        }
        __syncthreads();
#pragma unroll
        for (int ks = 0; ks < 2; ++ks) {
            bf16x8 af = *(const bf16x8*)&As[(w * 16 + l15) * AS + ks * 32 + quad * 8];
#pragma unroll
            for (int ct = 0; ct < 8; ++ct) {
                bf16x8 bf = *(const bf16x8*)&Ws[(ct * 16 + l15) * AS + ks * 32 + quad * 8];
                acc[ct] = __builtin_amdgcn_mfma_f32_16x16x32_bf16(af, bf, acc[ct], 0, 0, 0);
            }
        }
        __syncthreads();
    }

    // ---- epilogue: C tile -> LDS (64 x 132 fp32) ----
    float* Cs = smem;
#pragma unroll
    for (int ct = 0; ct < 8; ++ct)
#pragma unroll
        for (int r = 0; r < 4; ++r)
            Cs[(w * 16 + quad * 4 + r) * 132 + ct * 16 + l15] = acc[ct][r];
    __syncthreads();

    if (L2MODE) {
#pragma unroll
        for (int t = 0; t < 2; ++t) {
            int chunk = tid + t * 256;
            int r = chunk >> 3, c8 = chunk & 7;
            int grow = row0 + r;
            if (grow < nrows) {
                float4 v0 = *(float4*)&Cs[r * 132 + c8 * 8];
                float4 v1 = *(float4*)&Cs[r * 132 + c8 * 8 + 4];
                *(uint4*)&Hb[(size_t)grow * 64 + c8 * 8] = pack8(v0, v1);
            }
        }
#pragma unroll
        for (int t = 0; t < 4; ++t) {
            int chunk = tid + t * 256;
            int r = chunk >> 4, c4 = chunk & 15;
            int grow = row0 + r;
            if (grow < nrows)
                *(float4*)&hres[(size_t)grow * 64 + c4 * 4] =
                    *(float4*)&Cs[r * 132 + 64 + c4 * 4];
        }
    } else {
#pragma unroll
        for (int t = 0; t < 4; ++t) {
            int chunk = tid + t * 256;
            int r = chunk >> 4, c8 = chunk & 15;
            int grow = row0 + r;
            if (grow < nrows) {
                float4 v0 = *(float4*)&Cs[r * 132 + c8 * 8];
                float4 v1 = *(float4*)&Cs[r * 132 + c8 * 8 + 4];
                *(uint4*)&Hb[(size_t)grow * 128 + c8 * 8] = pack8(v0, v1);
            }
        }
    }
    // el/er: 64 rows x 2 heads x {el,er} = 256 threads
    {
        constexpr int HD = L2MODE ? 32 : 64;
        int r = tid >> 2, hh = (tid >> 1) & 1, iser = tid & 1;
        int grow = row0 + r;
        const float* coef = alr + iser * NC + hh * HD;
        const float* crow = Cs + r * 132 + hh * HD;
        float sum = 0.f;
#pragma unroll
        for (int i = 0; i < HD; ++i) sum += crow[i] * coef[i];
        if (grow < nrows) (iser ? er : el)[grow * 2 + hh] = sum;
    }
}

// ---------------------------------------------------------------------------
// Aggregation, bf16 gather with 4-deep load batching: one wave per node.
// Row = 2*D bf16 = CH uint4 chunks; ES = 64/CH edges per wave-load; inner
// loop issues UB=4 independent gathers (4*ES edges) before consuming ->
// ~4x memory-level parallelism vs the rolled loop (VGPR 24 -> ~48).
// ---------------------------------------------------------------------------
template <int D, bool MEAN_HEADS>
__global__ __launch_bounds__(256) void agg_b(
    const int* __restrict__ ssrc, const int* __restrict__ offs,
    const int* __restrict__ deg, const ushort* __restrict__ hb,
    const float* __restrict__ el, const float* __restrict__ er,
    const float* __restrict__ bias, const float* __restrict__ res,
    float* __restrict__ out, ushort* __restrict__ outb, int act, int n) {
    constexpr int F = 2 * D;
    constexpr int CH = F / 8;
    constexpr int ES = 64 / CH;
    constexpr int UB = 4;          // load-batch depth
    const int wid = threadIdx.x >> 6;
    const int lane = threadIdx.x & 63;
    const int node = blockIdx.x * 4 + wid;
    if (node >= n) return;
    const int off = offs[node];
    const int dg = deg[node];
    const float2 ern = *(const float2*)&er[node * 2];

    float m0, m1, is0, is1;
    float w0r = 0.f, w1r = 0.f;
    int sidx_r = 0;
    const bool small = (dg <= 64);
    if (small) {
        float a = -INFINITY, b = -INFINITY;
        if (lane < dg) {
            sidx_r = ssrc[off + lane];
            float2 ev = *(const float2*)&el[sidx_r * 2];
            a = ev.x + ern.x; a = a >= 0.f ? a : 0.2f * a;
            b = ev.y + ern.y; b = b >= 0.f ? b : 0.2f * b;
        }
        m0 = a; m1 = b;
        for (int o = 32; o; o >>= 1) {
            m0 = fmaxf(m0, __shfl_xor(m0, o));
            m1 = fmaxf(m1, __shfl_xor(m1, o));
        }
        float p0 = (lane < dg) ? __expf(a - m0) : 0.f;
        float p1 = (lane < dg) ? __expf(b - m1) : 0.f;
        float s0 = p0, s1 = p1;
        for (int o = 32; o; o >>= 1) {
            s0 += __shfl_xor(s0, o);
            s1 += __shfl_xor(s1, o);
        }
        is0 = s0 > 0.f ? 1.f / s0 : 0.f;
        is1 = s1 > 0.f ? 1.f / s1 : 0.f;
        w0r = p0 * is0;
        w1r = p1 * is1;
    } else {
        float s0 = 0.f, s1 = 0.f;
        m0 = -INFINITY; m1 = -INFINITY;
        for (int k = lane; k < dg; k += 64) {
            int sidx = ssrc[off + k];
            float2 ev = *(const float2*)&el[sidx * 2];
            float a = ev.x + ern.x; a = a >= 0.f ? a : 0.2f * a;
            float b = ev.y + ern.y; b = b >= 0.f ? b : 0.2f * b;
            float nm = fmaxf(m0, a);
            s0 = s0 * __expf(m0 - nm) + __expf(a - nm); m0 = nm;
            nm = fmaxf(m1, b);
            s1 = s1 * __expf(m1 - nm) + __expf(b - nm); m1 = nm;
        }
        for (int o = 32; o; o >>= 1) {
            float om = __shfl_xor(m0, o), os = __shfl_xor(s0, o);
            float nm = fmaxf(m0, om);
            s0 = (nm == -INFINITY) ? 0.f : s0 * __expf(m0 - nm) + os * __expf(om - nm);
            m0 = nm;
            om = __shfl_xor(m1, o); os = __shfl_xor(s1, o);
            nm = fmaxf(m1, om);
            s1 = (nm == -INFINITY) ? 0.f : s1 * __expf(m1 - nm) + os * __expf(om - nm);
            m1 = nm;
        }
        is0 = s0 > 0.f ? 1.f / s0 : 0.f;
        is1 = s1 > 0.f ? 1.f / s1 : 0.f;
    }

    const int c = lane & (CH - 1);
    const int es = lane / CH;
    const bool head1 = (c >= CH / 2);
    const uint4* __restrict__ hp = (const uint4*)hb;
    float acc[8];
#pragma unroll
    for (int i = 0; i < 8; ++i) acc[i] = 0.f;

    for (int c0 = 0; c0 < dg; c0 += 64) {
        float w0, w1;
        int sidx;
        if (small) {
            sidx = sidx_r; w0 = w0r; w1 = w1r;
        } else {
            int k = c0 + lane;
            if (k < dg) {
                sidx = ssrc[off + k];
                float2 ev = *(const float2*)&el[sidx * 2];
                float a = ev.x + ern.x; a = a >= 0.f ? a : 0.2f * a;
                float b = ev.y + ern.y; b = b >= 0.f ? b : 0.2f * b;
                w0 = __expf(a - m0) * is0;
                w1 = __expf(b - m1) * is1;
            } else {
                sidx = 0; w0 = 0.f; w1 = 0.f;
            }
        }
        const int cnt = min(64, dg - c0);
        // batched: UB independent gathers in flight before any FMA
        for (int p = 0; p < cnt; p += UB * ES) {
            uint4 q[UB];
            float wj[UB];
#pragma unroll
            for (int u = 0; u < UB; ++u) {
                int j = p + u * ES + es;
                int jc = (j < cnt) ? j : 0;
                int sj = __shfl(sidx, jc);
                float wa = __shfl(w0, jc);
                float wb = __shfl(w1, jc);
                wj[u] = (j < cnt) ? (head1 ? wb : wa) : 0.f;
                q[u] = hp[(size_t)sj * CH + c];
            }
#pragma unroll
            for (int u = 0; u < UB; ++u) {
                acc[0] += wj[u] * __uint_as_float(q[u].x << 16);
                acc[1] += wj[u] * __uint_as_float(q[u].x & 0xffff0000u);
                acc[2] += wj[u] * __uint_as_float(q[u].y << 16);
                acc[3] += wj[u] * __uint_as_float(q[u].y & 0xffff0000u);
                acc[4] += wj[u] * __uint_as_float(q[u].z << 16);
                acc[5] += wj[u] * __uint_as_float(q[u].z & 0xffff0000u);
                acc[6] += wj[u] * __uint_as_float(q[u].w << 16);
                acc[7] += wj[u] * __uint_as_float(q[u].w & 0xffff0000u);
            }
        }
    }

#pragma unroll
    for (int o = CH; o < 64; o <<= 1) {
#pragma unroll
        for (int i = 0; i < 8; ++i) acc[i] += __shfl_xor(acc[i], o);
    }

    const int f0 = c * 8;
    float4 b0v = *(const float4*)&bias[f0];
    float4 b1v = *(const float4*)&bias[f0 + 4];
    float vv[8] = {acc[0] + b0v.x, acc[1] + b0v.y, acc[2] + b0v.z, acc[3] + b0v.w,
                   acc[4] + b1v.x, acc[5] + b1v.y, acc[6] + b1v.z, acc[7] + b1v.w};
    if (res) {
        float4 r0v = *(const float4*)&res[(size_t)node * F + f0];
        float4 r1v = *(const float4*)&res[(size_t)node * F + f0 + 4];
        vv[0] += r0v.x; vv[1] += r0v.y; vv[2] += r0v.z; vv[3] += r0v.w;
        vv[4] += r1v.x; vv[5] += r1v.y; vv[6] += r1v.z; vv[7] += r1v.w;
    }
    if (act) {
#pragma unroll
        for (int i = 0; i < 8; ++i)
            vv[i] = vv[i] > 0.f ? vv[i] : __expf(vv[i]) - 1.f;
    }
    if (MEAN_HEADS) {
        float ov[8];
#pragma unroll
        for (int i = 0; i < 8; ++i) ov[i] = __shfl_xor(vv[i], CH / 2);
        if (es == 0 && c < CH / 2) {
            float4 u0 = make_float4(0.5f * (vv[0] + ov[0]), 0.5f * (vv[1] + ov[1]),
                                    0.5f * (vv[2] + ov[2]), 0.5f * (vv[3] + ov[3]));
            float4 u1 = make_float4(0.5f * (vv[4] + ov[4]), 0.5f * (vv[5] + ov[5]),
                                    0.5f * (vv[6] + ov[6]), 0.5f * (vv[7] + ov[7]));
            *(float4*)&out[(size_t)node * D + f0] = u0;
            *(float4*)&out[(size_t)node * D + f0 + 4] = u1;
        }
    } else if (es == 0) {
        if (out) {
            *(float4*)&out[(size_t)node * F + f0] =
                make_float4(vv[0], vv[1], vv[2], vv[3]);
            *(float4*)&out[(size_t)node * F + f0 + 4] =
                make_float4(vv[4], vv[5], vv[6], vv[7]);
        }
        if (outb) {
            *(uint4*)&outb[(size_t)node * F + f0] =
                pack8(make_float4(vv[0], vv[1], vv[2], vv[3]),
                      make_float4(vv[4], vv[5], vv[6], vv[7]));
        }
    }
}

// ---------------------------------------------------------------------------

extern "C" void kernel_launch(void* const* d_in, const int* in_sizes, int n_in,
                              void* d_out, int out_size, void* d_ws, size_t ws_size,
                              hipStream_t stream) {
    const float* x     = (const float*)d_in[0];
    const int*   esrc  = (const int*)d_in[1];
    const int*   edst  = (const int*)d_in[2];
    const float* W0    = (const float*)d_in[3];
    const float* al0   = (const float*)d_in[4];
    const float* ar0   = (const float*)d_in[5];
    const float* b0    = (const float*)d_in[6];
    const float* W1    = (const float*)d_in[7];
    const float* al1   = (const float*)d_in[8];
    const float* ar1   = (const float*)d_in[9];
    const float* b1    = (const float*)d_in[10];
    const float* W2    = (const float*)d_in[11];
    const float* al2   = (const float*)d_in[12];
    const float* ar2   = (const float*)d_in[13];
    const float* b2    = (const float*)d_in[14];
    const float* Wres2 = (const float*)d_in[15];

    const int N = in_sizes[0] / 256;  // 50000
    const int E = in_sizes[1];        // 800000

    // workspace layout
    float* ws = (float*)d_ws;
    float* A     = ws;                      // [N,128] fp32 agg0 out (L1 residual)
    float* hres  = A + (size_t)N * 128;     // [N,64]  L2 projected residual
    float* el    = hres + (size_t)N * 64;   // [N,2]
    float* er    = el + (size_t)N * 2;      // [N,2]
    int* deg     = (int*)(er + (size_t)N * 2);
    int* offs    = deg + N;
    int* cursor  = offs + N;
    int* incl    = cursor + N;
    int* bsums   = incl + N;                // 256 ints
    int* ssrc    = bsums + 256;             // [E]
    ushort* Hb   = (ushort*)(ssrc + E);     // [N,128] bf16 gemm out (gather src)
    ushort* Ab   = Hb + (size_t)N * 128;    // [N,128] bf16 agg0 out (L1 gemm in)
    ushort* Bb   = Ab + (size_t)N * 128;    // [N,128] bf16 agg1 out (L2 gemm in)
    ushort* Wt0  = Bb + (size_t)N * 128;    // [128,256] bf16 W0^T
    ushort* Wt1  = Wt0 + 128 * 256;         // [128,128] bf16 W1^T
    ushort* Wt2c = Wt1 + 128 * 128;         // [128,128] bf16 [W2|Wres2]^T

    // ---- CSR-by-destination build ----
    hipMemsetAsync(deg, 0, (size_t)N * sizeof(int), stream);
    hipMemsetAsync(cursor, 0, (size_t)N * sizeof(int), stream);
    hist_k<<<(E + 255) / 256, 256, 0, stream>>>(edst, E, deg);
    int nb = (N + 511) / 512;  // 98 <= 128
    scan1_k<<<nb, 512, 0, stream>>>(deg, N, incl, bsums);
    scan2_k<<<1, 128, 0, stream>>>(bsums, nb);
    scan3_k<<<(N + 255) / 256, 256, 0, stream>>>(incl, deg, bsums, offs, N);
    scatter_k<<<(E + 255) / 256, 256, 0, stream>>>(esrc, edst, E, offs, cursor, ssrc);

    // ---- weight prep ----
    wt_k<<<256, 256, 0, stream>>>(W0, W1, W2, Wres2, Wt0, Wt1, Wt2c);

    int gblk = (N + 63) / 64;  // 782
    int ablk = (N + 3) / 4;    // wave per node

    // ---- Layer 0: IN=256 -> [N,2,64], ELU ----
    gemm_m<256, false, true><<<gblk, 256, 0, stream>>>(
        x, nullptr, Wt0, Hb, nullptr, N, al0, ar0, el, er);
    agg_b<64, false><<<ablk, 256, 0, stream>>>(ssrc, offs, deg, Hb, el, er, b0,
                                               nullptr, A, Ab, 1, N);

    // ---- Layer 1: 128 -> [N,2,64], identity residual (A), ELU ----
    gemm_m<128, false, false><<<gblk, 256, 0, stream>>>(
        nullptr, Ab, Wt1, Hb, nullptr, N, al1, ar1, el, er);
    agg_b<64, false><<<ablk, 256, 0, stream>>>(ssrc, offs, deg, Hb, el, er, b1,
                                               A, nullptr, Bb, 1, N);

    // ---- Layer 2: 128 -> [N,2,32], W2+Wres2 fused, head-mean ----
    gemm_m<128, true, false><<<gblk, 256, 0, stream>>>(
        nullptr, Bb, Wt2c, Hb, hres, N, al2, ar2, el, er);
    agg_b<32, true><<<ablk, 256, 0, stream>>>(ssrc, offs, deg, Hb, el, er, b2,
                                              hres, (float*)d_out, nullptr, 0, N);
}